// Round 2
// baseline (793.719 us; speedup 1.0000x reference)
//
#include <hip/hip_runtime.h>
#include <stdint.h>

// CrossAttention, fp32/bf16 I/O autodetect, all-bf16 MFMA pipeline.
// R7: gemm8 schedule repair — (a) all staging moved to read-free phases
// (ph3/4 stage tile kt+2, ph7/8 stage tile kt+3) giving uniform vmcnt(8)
// drains with 4-5 phase prefetch distance; (b) counted lgkmcnt(4/8/4/0)
// with sched_barrier-pinned read order so LDS bursts overlap MFMA.
// L2 (N=512) stays on proven gemm_bt; fallback path untouched.

typedef __attribute__((ext_vector_type(8))) short bf16x8;
typedef __attribute__((ext_vector_type(4))) float f32x4;
typedef __attribute__((ext_vector_type(8))) unsigned short u16x8;

__device__ __forceinline__ float bf2f(unsigned short u) {
    return __uint_as_float(((unsigned int)u) << 16);
}
__device__ __forceinline__ unsigned short f2bf(float f) {
    unsigned int u = __float_as_uint(f);
    unsigned int r = (u + 0x7fffu + ((u >> 16) & 1u)) >> 16;
    return (unsigned short)r;
}

__device__ __forceinline__ void async16(const void* g, void* l) {
    __builtin_amdgcn_global_load_lds(
        (const __attribute__((address_space(1))) unsigned int*)g,
        (__attribute__((address_space(3))) unsigned int*)l,
        16, 0, 0);
}

// ---------------------------------------------------------------------------
__global__ __launch_bounds__(64) void detect_dtype(
    const unsigned short* __restrict__ w, int* __restrict__ flag)
{
    const int t = threadIdx.x;
    int cnt = 0;
    for (int i = t; i < 4096; i += 64) {
        const unsigned e = (w[i] >> 7) & 0xFF;
        cnt += (e >= 140) ? 1 : 0;
    }
#pragma unroll
    for (int off = 32; off; off >>= 1) cnt += __shfl_xor(cnt, off, 64);
    if (t == 0) flag[0] = (cnt >= 8) ? 1 : 0;
}

// ---------------------------------------------------------------------------
__global__ __launch_bounds__(256) void conv_bias_all(
    const void* b1, const void* b2, const void* b3, const void* b4,
    const void* bq, const void* bk, const void* bv,
    float* __restrict__ out, const int* __restrict__ flag)
{
    const int i = blockIdx.x * 256 + threadIdx.x;
    const int slot = i >> 10, idx = i & 1023;
    if (slot == 1 && idx >= 512) return;
    const void* src = (slot == 0) ? b1 : (slot == 1) ? b2 : (slot == 2) ? b3 :
                      (slot == 3) ? b4 : (slot == 4) ? bq : (slot == 5) ? bk : bv;
    out[i] = (*flag) ? ((const float*)src)[idx]
                     : bf2f(((const unsigned short*)src)[idx]);
}

// ---------------------------------------------------------------------------
__device__ __forceinline__ void wt_body(
    const void* in, unsigned short* out, int R, int C, int f)
{
    __shared__ unsigned short tile[32][33];
    const int bc = blockIdx.x * 32;
    const int br = blockIdx.y * 32;
    const int x = threadIdx.x & 31;
    const int y = threadIdx.x >> 5;
#pragma unroll
    for (int i = 0; i < 4; i++) {
        const int r = y + i * 8;
        unsigned short v;
        if (f) v = f2bf(((const float*)in)[(size_t)(br + r) * C + bc + x]);
        else   v = ((const unsigned short*)in)[(size_t)(br + r) * C + bc + x];
        tile[r][x] = v;
    }
    __syncthreads();
#pragma unroll
    for (int i = 0; i < 4; i++) {
        const int r = y + i * 8;
        out[(size_t)(bc + r) * R + br + x] = tile[x][r];
    }
}

__global__ __launch_bounds__(256) void conv_weight_t7(
    const void* i0, unsigned short* o0, const void* i1, unsigned short* o1,
    const void* i2, unsigned short* o2, const void* i3, unsigned short* o3,
    const void* i4, unsigned short* o4, const void* i5, unsigned short* o5,
    const void* i6, unsigned short* o6, const int* flag)
{
    const int z = blockIdx.z;
    if (z == 5) {
        if (blockIdx.x >= 16) return;
        wt_body(i5, o5, 1024, 512, *flag);
        return;
    }
    if (z == 6) {
        if (blockIdx.y >= 16) return;
        wt_body(i6, o6, 512, 1024, *flag);
        return;
    }
    const void* in = (z == 0) ? i0 : (z == 1) ? i1 : (z == 2) ? i2 : (z == 3) ? i3 : i4;
    unsigned short* out = (z == 0) ? o0 : (z == 1) ? o1 : (z == 2) ? o2 : (z == 3) ? o3 : o4;
    wt_body(in, out, 1024, 1024, *flag);
}

__global__ __launch_bounds__(256) void conv_to_bf16(
    const void* __restrict__ in, unsigned short* __restrict__ out,
    int n, const int* __restrict__ flag)
{
    const int i = (blockIdx.x * 256 + threadIdx.x) * 8;
    if (i >= n) return;
    if (*flag) {
        const float4* p = (const float4*)((const float*)in + i);
        const float4 a = p[0], b = p[1];
        u16x8 o;
        o[0] = f2bf(a.x); o[1] = f2bf(a.y); o[2] = f2bf(a.z); o[3] = f2bf(a.w);
        o[4] = f2bf(b.x); o[5] = f2bf(b.y); o[6] = f2bf(b.z); o[7] = f2bf(b.w);
        *(u16x8*)(out + i) = o;
    } else {
        *(u16x8*)(out + i) = *(const u16x8*)((const unsigned short*)in + i);
    }
}

__global__ __launch_bounds__(256) void write_out(
    const unsigned short* __restrict__ src, void* __restrict__ dst,
    int n, const int* __restrict__ flag)
{
    const int i = (blockIdx.x * 256 + threadIdx.x) * 8;
    if (i >= n) return;
    const u16x8 v = *(const u16x8*)(src + i);
    if (*flag) {
        float4 a, b;
        a.x = bf2f(v[0]); a.y = bf2f(v[1]); a.z = bf2f(v[2]); a.w = bf2f(v[3]);
        b.x = bf2f(v[4]); b.y = bf2f(v[5]); b.z = bf2f(v[6]); b.w = bf2f(v[7]);
        float4* p = (float4*)((float*)dst + i);
        p[0] = a; p[1] = b;
    } else {
        *(u16x8*)((unsigned short*)dst + i) = v;
    }
}

// ---------------------------------------------------------------------------
// Proven 128x128 GEMM (R3/R4): C = act(alpha*A@B^T + bias). Kept for L2
// (N=512) and the low-workspace fallback path.
// ---------------------------------------------------------------------------
template <int RELU, int BIAS, int OUTF, int SWZ>
__global__ __launch_bounds__(256, 2) void gemm_bt(
    const unsigned short* __restrict__ A, const unsigned short* __restrict__ B,
    const float* __restrict__ bias, void* __restrict__ C,
    int M, int N, int K, float alpha,
    long long sA, long long sB, long long sC, const int* __restrict__ flag)
{
    int bxi = blockIdx.x, byi = blockIdx.y;
    if (SWZ) {
        const int id = byi * gridDim.x + bxi;
        bxi = (id >> 3) % gridDim.x;
        byi = (id >> 3) / gridDim.x * 8 + (id & 7);
    }
    const int z = blockIdx.z;
    A += (size_t)z * (size_t)sA;
    B += (size_t)z * (size_t)sB;
    const size_t cofs = (size_t)z * (size_t)sC;

    const int bm = byi * 128;
    const int bn = bxi * 128;
    const int t = threadIdx.x;
    const int lane = t & 63;
    const int w = t >> 6;
    const int wr = (w >> 1) * 64;
    const int wc = (w & 1) * 64;

    __shared__ unsigned short sAt[128 * 32];
    __shared__ unsigned short sBt[128 * 32];

    f32x4 acc[4][4];
#pragma unroll
    for (int i = 0; i < 4; i++)
#pragma unroll
        for (int j = 0; j < 4; j++)
            acc[i][j] = (f32x4){0.f, 0.f, 0.f, 0.f};

    const int tr = t >> 2;
    const int tc = (t & 3) << 3;
    const unsigned short* ga = A + (size_t)(bm + tr) * K + tc;
    const unsigned short* gb = B + (size_t)(bn + tr) * K + tc;
    unsigned short* la = &sAt[tr * 32 + tc];
    unsigned short* lb = &sBt[tr * 32 + tc];

    const int am = wr + (lane & 15);
    const int bn_ = wc + (lane & 15);
    const int ak = (lane >> 4) * 8;

    for (int k0 = 0; k0 < K; k0 += 32) {
        async16(ga, la);
        async16(ga + (size_t)64 * K, la + 64 * 32);
        async16(gb, lb);
        async16(gb + (size_t)64 * K, lb + 64 * 32);
        ga += 32;
        gb += 32;
        __syncthreads();

        bf16x8 af[4], bfr[4];
#pragma unroll
        for (int i = 0; i < 4; i++)
            af[i] = *(const bf16x8*)&sAt[(am + i * 16) * 32 + ak];
#pragma unroll
        for (int j = 0; j < 4; j++)
            bfr[j] = *(const bf16x8*)&sBt[(bn_ + j * 16) * 32 + ak];
#pragma unroll
        for (int i = 0; i < 4; i++)
#pragma unroll
            for (int j = 0; j < 4; j++)
                acc[i][j] = __builtin_amdgcn_mfma_f32_16x16x32_bf16(
                    af[i], bfr[j], acc[i][j], 0, 0, 0);
        __syncthreads();
    }

    const int fl = OUTF ? *flag : 0;
#pragma unroll
    for (int i = 0; i < 4; i++) {
        const int row0 = bm + wr + i * 16 + (lane >> 4) * 4;
#pragma unroll
        for (int j = 0; j < 4; j++) {
            const int col = bn + wc + j * 16 + (lane & 15);
            float bc = 0.f;
            if (BIAS == 1) bc = bias[col];
#pragma unroll
            for (int r = 0; r < 4; r++) {
                float bv = bc;
                if (BIAS == 2) bv = bias[row0 + r];
                float vv = acc[i][j][r] * alpha + bv;
                if (RELU) vv = fmaxf(vv, 0.f);
                const size_t idx = cofs + (size_t)(row0 + r) * N + col;
                if (OUTF && fl) ((float*)C)[idx] = vv;
                else ((unsigned short*)C)[idx] = f2bf(vv);
            }
        }
    }
}

// ---------------------------------------------------------------------------
// R7: 256x256 tile, BK=64, 8 waves (512 thr), 8-phase schedule per 2 K-tiles.
// Phase layout (read-phases 1,2,5,6; stage-phases 3,4,7,8):
//   ph1: rd buf0 {aL0,bb0 | aL1}            lgkm(4)  16 MFMA
//   ph2: rd buf0 {bb1 | aH0 | aH1}          lgkm(8)  16 MFMA
//   ph3: stage A(kt+2)h0 + B(kt+2)h0        lgkm(4)  16 MFMA
//   ph4: stage A(kt+2)h1 + B(kt+2)h1        lgkm(0)  16 MFMA  vmcnt(8)
//   ph5..8: same on buf1, staging tile kt+3,          vmcnt(8)
// Both drains wait only on loads issued 4-5 phases (~2000cy) earlier.
// Requires M%256==0, N%256==0, K%128==0, K>=256.
// ---------------------------------------------------------------------------
#define G8_STG(gbase, dbase, T, h) do {                                        \
    const unsigned short* _s = (gbase) + (size_t)((h) * 128) * K               \
                                       + (size_t)(T) * 64;                     \
    unsigned short* _d = (dbase) + (((T) & 1) ? 16384 : 0) + (h) * 8192;       \
    async16(_s, _d);                                                           \
    async16(_s + (size_t)64 * K, _d + 4096);                                   \
} while (0)

// ph1/ph5 reads: aL0 x4, bb0 x4  ||  aL1 x4   (boundary pinned)
#define G8_RDA(PA_, PB_)                                                       \
    _Pragma("unroll")                                                          \
    for (int m_ = 0; m_ < 4; m_++)                                             \
        aL[m_][0] = *(const bf16x8*)&(PA_)[rA + m_ * 1024 + c0];               \
    _Pragma("unroll")                                                          \
    for (int n_ = 0; n_ < 4; n_++)                                             \
        bb[n_][0] = *(const bf16x8*)&(PB_)[rB + n_ * 1024 + c0];               \
    __builtin_amdgcn_sched_barrier(0);                                         \
    _Pragma("unroll")                                                          \
    for (int m_ = 0; m_ < 4; m_++)                                             \
        aL[m_][1] = *(const bf16x8*)&(PA_)[rA + m_ * 1024 + c1];

// ph2/ph6 reads: bb1 x4 || aH0 x4 || aH1 x4   (boundaries pinned)
#define G8_RDB(PA_, PB_)                                                       \
    _Pragma("unroll")                                                          \
    for (int n_ = 0; n_ < 4; n_++)                                             \
        bb[n_][1] = *(const bf16x8*)&(PB_)[rB + n_ * 1024 + c1];               \
    __builtin_amdgcn_sched_barrier(0);                                         \
    _Pragma("unroll")                                                          \
    for (int m_ = 0; m_ < 4; m_++)                                             \
        aH[m_][0] = *(const bf16x8*)&(PA_)[rA + (m_ + 4) * 1024 + c0];         \
    __builtin_amdgcn_sched_barrier(0);                                         \
    _Pragma("unroll")                                                          \
    for (int m_ = 0; m_ < 4; m_++)                                             \
        aH[m_][1] = *(const bf16x8*)&(PA_)[rA + (m_ + 4) * 1024 + c1];

#define G8_TOP(LG)                                                             \
    __builtin_amdgcn_s_barrier();                                              \
    asm volatile("s_waitcnt lgkmcnt(" #LG ")" ::: "memory");                   \
    __builtin_amdgcn_sched_barrier(0);                                         \
    __builtin_amdgcn_s_setprio(1);

#define G8_FMA(AF, KK, MOFS)                                                   \
    _Pragma("unroll")                                                          \
    for (int m_ = 0; m_ < 4; m_++) {                                           \
        _Pragma("unroll")                                                      \
        for (int n_ = 0; n_ < 4; n_++)                                         \
            acc[(MOFS) + m_][n_] = __builtin_amdgcn_mfma_f32_16x16x32_bf16(    \
                AF[m_][KK], bb[n_][KK], acc[(MOFS) + m_][n_], 0, 0, 0);        \
    }

#define G8_BOT()                                                               \
    __builtin_amdgcn_s_setprio(0);                                             \
    asm volatile("" ::: "memory");                                             \
    __builtin_amdgcn_s_barrier();                                              \
    asm volatile("" ::: "memory");

#define G8_BOTVM(N)                                                            \
    __builtin_amdgcn_s_setprio(0);                                             \
    asm volatile("s_waitcnt vmcnt(" #N ")" ::: "memory");                      \
    __builtin_amdgcn_s_barrier();                                              \
    asm volatile("" ::: "memory");

template <int RELU, int BIAS, int OUTF, int SWZ>
__global__ __launch_bounds__(512, 2) void gemm8(
    const unsigned short* __restrict__ A, const unsigned short* __restrict__ B,
    const float* __restrict__ bias, void* __restrict__ C,
    int M, int N, int K, float alpha,
    long long sA, long long sB, long long sC, const int* __restrict__ flag)
{
    extern __shared__ unsigned short lds[];
    (void)M;
    int bxi = blockIdx.x, byi = blockIdx.y;
    if (SWZ) {
        const int id = byi * gridDim.x + bxi;
        bxi = (id >> 3) % gridDim.x;
        byi = (id >> 3) / gridDim.x * 8 + (id & 7);
    }
    const int z = blockIdx.z;
    A += (size_t)z * (size_t)sA;
    B += (size_t)z * (size_t)sB;
    const size_t cofs = (size_t)z * (size_t)sC;

    const int bm = byi * 256;
    const int bn = bxi * 256;
    const int t = threadIdx.x;
    const int lane = t & 63;
    const int w = t >> 6;
    const int wm = w >> 2;   // 0..1  (128 output rows each)
    const int wn = w & 3;    // 0..3  (64 output cols each)

    unsigned short* LA = lds;            // [2][256][64] A panels
    unsigned short* LB = lds + 32768;    // [2][256][64] B panels

    // --- staging: linear LDS dest, inverse-swizzled global source (T2) ---
    const int rowi = t >> 3;                          // 0..63
    const int co = ((t & 7) ^ (rowi & 7)) << 3;       // swizzled k-col (elems)
    const unsigned short* gA = A + (size_t)(bm + rowi) * K + co;
    const unsigned short* gB = B + (size_t)(bn + rowi) * K + co;
    unsigned short* dA = LA + t * 8;
    unsigned short* dB = LB + t * 8;

    // --- swizzled ds_read offsets (halfs) ---
    const int rA = (wm * 128 + (lane & 15)) * 64;
    const int rB = (wn * 64 + (lane & 15)) * 64;
    const int swz = (lane & 7) << 4;                  // byte swizzle
    const int c0 = ((((lane >> 4) << 4)) ^ swz) >> 1; // k0 slice, halfs
    const int c1 = ((64 | ((lane >> 4) << 4)) ^ swz) >> 1; // k1 slice

    f32x4 acc[8][4];
#pragma unroll
    for (int i = 0; i < 8; i++)
#pragma unroll
        for (int j = 0; j < 4; j++)
            acc[i][j] = (f32x4){0.f, 0.f, 0.f, 0.f};

    bf16x8 aL[4][2], aH[4][2], bb[4][2];

    // prologue: tile0 + tile1 fully staged (16 loads); drain tile0 only.
    G8_STG(gA, dA, 0, 0);
    G8_STG(gA, dA, 0, 1);
    G8_STG(gB, dB, 0, 0);
    G8_STG(gB, dB, 0, 1);
    G8_STG(gA, dA, 1, 0);
    G8_STG(gA, dA, 1, 1);
    G8_STG(gB, dB, 1, 0);
    G8_STG(gB, dB, 1, 1);
    asm volatile("s_waitcnt vmcnt(8)" ::: "memory");
    __builtin_amdgcn_s_barrier();
    asm volatile("" ::: "memory");

    const int NI = K >> 7;   // iterations, 2 K-tiles (of 64) each
    int kt = 0;
    for (int i = 0; i < NI - 1; ++i, kt += 2) {
        // ph1: read buf0 {aL0,bb0|aL1}
        G8_RDA(LA, LB)
        G8_TOP(4)
        G8_FMA(aL, 0, 0)
        G8_BOT()
        // ph2: read buf0 {bb1|aH0|aH1}
        G8_RDB(LA, LB)
        G8_TOP(8)
        G8_FMA(aL, 1, 0)
        G8_BOT()
        // ph3: stage tile kt+2 h0 (A+B) into buf0 (dead since ph2)
        G8_STG(gA, dA, kt + 2, 0);
        G8_STG(gB, dB, kt + 2, 0);
        G8_TOP(4)
        G8_FMA(aH, 0, 4)
        G8_BOT()
        // ph4: stage tile kt+2 h1 ; vmcnt(8) drains tile kt+1 for ph5
        G8_STG(gA, dA, kt + 2, 1);
        G8_STG(gB, dB, kt + 2, 1);
        G8_TOP(0)
        G8_FMA(aH, 1, 4)
        G8_BOTVM(8)
        // ph5: read buf1 {aL0,bb0|aL1}
        G8_RDA((LA + 16384), (LB + 16384))
        G8_TOP(4)
        G8_FMA(aL, 0, 0)
        G8_BOT()
        // ph6: read buf1 {bb1|aH0|aH1}
        G8_RDB((LA + 16384), (LB + 16384))
        G8_TOP(8)
        G8_FMA(aL, 1, 0)
        G8_BOT()
        // ph7: stage tile kt+3 h0 into buf1 (dead since ph6)
        G8_STG(gA, dA, kt + 3, 0);
        G8_STG(gB, dB, kt + 3, 0);
        G8_TOP(4)
        G8_FMA(aH, 0, 4)
        G8_BOT()
        // ph8: stage tile kt+3 h1 ; vmcnt(8) drains tile kt+2 for next ph1
        G8_STG(gA, dA, kt + 3, 1);
        G8_STG(gB, dB, kt + 3, 1);
        G8_TOP(0)
        G8_FMA(aH, 1, 4)
        G8_BOTVM(8)
    }
    // final iteration: tiles kt (buf0), kt+1 (buf1); no staging left.
    {
        G8_RDA(LA, LB)
        G8_TOP(4)
        G8_FMA(aL, 0, 0)
        G8_BOT()
        G8_RDB(LA, LB)
        G8_TOP(8)
        G8_FMA(aL, 1, 0)
        G8_BOT()
        G8_TOP(4)
        G8_FMA(aH, 0, 4)
        G8_BOT()
        G8_TOP(0)
        G8_FMA(aH, 1, 4)
        G8_BOTVM(0)
        G8_RDA((LA + 16384), (LB + 16384))
        G8_TOP(4)
        G8_FMA(aL, 0, 0)
        G8_BOT()
        G8_RDB((LA + 16384), (LB + 16384))
        G8_TOP(8)
        G8_FMA(aL, 1, 0)
        G8_BOT()
        G8_TOP(4)
        G8_FMA(aH, 0, 4)
        G8_BOT()
        G8_TOP(0)
        G8_FMA(aH, 1, 4)
        __builtin_amdgcn_s_setprio(0);
    }

    const int fl = OUTF ? *flag : 0;
#pragma unroll
    for (int mi = 0; mi < 8; mi++) {
        const int row0 = bm + wm * 128 + mi * 16 + (lane >> 4) * 4;
#pragma unroll
        for (int n = 0; n < 4; n++) {
            const int col = bn + wn * 64 + n * 16 + (lane & 15);
            float bc = 0.f;
            if (BIAS == 1) bc = bias[col];
#pragma unroll
            for (int r = 0; r < 4; r++) {
                float bv = bc;
                if (BIAS == 2) bv = bias[row0 + r];
                float vv = acc[mi][n][r] * alpha + bv;
                if (RELU) vv = fmaxf(vv, 0.f);
                const size_t idx = cofs + (size_t)(row0 + r) * N + col;
                if (OUTF && fl) ((float*)C)[idx] = vv;
                else ((unsigned short*)C)[idx] = f2bf(vv);
            }
        }
    }
}

// ---------------------------------------------------------------------------
__global__ __launch_bounds__(256) void softmax_rows(unsigned short* S, int n)
{
    const size_t row = blockIdx.x;
    unsigned short* p = S + row * (size_t)n;
    const int t = threadIdx.x;
    const int lane = t & 63;
    const int wave = t >> 6;

    u16x8 v = *(const u16x8*)(p + t * 8);
    float f[8];
    float m = -3.0e38f;
#pragma unroll
    for (int i = 0; i < 8; i++) {
        f[i] = bf2f(v[i]);
        m = fmaxf(m, f[i]);
    }
#pragma unroll
    for (int off = 32; off; off >>= 1) m = fmaxf(m, __shfl_xor(m, off, 64));
    __shared__ float redm[4];
    if (lane == 0) redm[wave] = m;
    __syncthreads();
    m = fmaxf(fmaxf(redm[0], redm[1]), fmaxf(redm[2], redm[3]));

    float e[8];
    float s = 0.f;
#pragma unroll
    for (int i = 0; i < 8; i++) {
        e[i] = __expf(f[i] - m);
        s += e[i];
    }
#pragma unroll
    for (int off = 32; off; off >>= 1) s += __shfl_xor(s, off, 64);
    __shared__ float reds[4];
    if (lane == 0) reds[wave] = s;
    __syncthreads();
    s = reds[0] + reds[1] + reds[2] + reds[3];
    const float inv = 1.0f / s;

    u16x8 o;
#pragma unroll
    for (int i = 0; i < 8; i++) o[i] = f2bf(e[i] * inv);
    *(u16x8*)(p + t * 8) = o;
}

// ---------------------------------------------------------------------------
extern "C" void kernel_launch(void* const* d_in, const int* in_sizes, int n_in,
                              void* d_out, int out_size, void* d_ws, size_t ws_size,
                              hipStream_t stream)
{
    const void* x  = d_in[0];
    const void* y  = d_in[1];
    const void* W1 = d_in[2];
    const void* b1 = d_in[3];
    const void* W2 = d_in[4];
    const void* b2 = d_in[5];
    const void* W3 = d_in[6];
    const void* b3 = d_in[7];
    const void* W4 = d_in[8];
    const void* b4 = d_in[9];
    const void* Wq = d_in[10];
    const void* bq = d_in[11];
    const void* Wk = d_in[12];
    const void* bk = d_in[13];
    const void* Wv = d_in[14];
    const void* bv = d_in[15];

    int* flag = (int*)d_ws;
    float* fb = (float*)((char*)d_ws + 64);
    unsigned short* arena = (unsigned short*)((char*)d_ws + 64 + 7 * 1024 * 4);
    const size_t baseB = 64 + 7 * 1024 * 4;
    const size_t MEG = 1024ull * 1024ull;

    auto needB = [&](int G, bool direct) -> size_t {
        return baseB + 2ull * ((6 + 16 + (size_t)G * 6 + (direct ? 0 : 16)) * MEG);
    };
    int G; bool direct;
    if (ws_size >= needB(8, true))      { G = 8; direct = true;  }
    else if (ws_size >= needB(4, false)) { G = 4; direct = false; }
    else if (ws_size >= needB(2, false)) { G = 2; direct = false; }
    else                                 { G = 1; direct = false; }

    unsigned short* W1t = arena;
    unsigned short* W2t = W1t + 1 * MEG;
    unsigned short* W3t = W2t + MEG / 2;
    unsigned short* W4t = W3t + MEG / 2;
    unsigned short* Wqt = W4t + 1 * MEG;
    unsigned short* Wkt = Wqt + 1 * MEG;
    unsigned short* Wvt = Wkt + 1 * MEG;
    unsigned short* XC  = Wvt + 1 * MEG;
    unsigned short* VT  = XC + 16 * MEG;
    unsigned short* SBUF = VT + (size_t)G * 2 * MEG;
    unsigned short* OUTS = SBUF + (size_t)G * 4 * MEG;

    unsigned short* PA = (unsigned short*)d_out;
    unsigned short* PB = PA + 16 * MEG;

    float* fb1 = fb;
    float* fb2 = fb + 1024;
    float* fb3 = fb + 2048;
    float* fb4 = fb + 3072;
    float* fbq = fb + 4096;
    float* fbk = fb + 5120;
    float* fbv = fb + 6144;

    const dim3 blk(256);
    const dim3 blk8(512);
    const int LDS8 = 131072;
    const int NE = 16 * 1024 * 1024;
    const int Mx = 16384;
    const long long Z0 = 0;
    const long long sQK = 2048ll * 1024;
    const long long sS  = 2048ll * 2048;

    // allow 128 KiB dynamic LDS for every gemm8 instantiation we launch
    (void)hipFuncSetAttribute((const void*)&gemm8<1, 1, 0, 1>,
                              hipFuncAttributeMaxDynamicSharedMemorySize, LDS8);
    (void)hipFuncSetAttribute((const void*)&gemm8<0, 1, 0, 1>,
                              hipFuncAttributeMaxDynamicSharedMemorySize, LDS8);
    (void)hipFuncSetAttribute((const void*)&gemm8<0, 2, 0, 0>,
                              hipFuncAttributeMaxDynamicSharedMemorySize, LDS8);
    (void)hipFuncSetAttribute((const void*)&gemm8<0, 0, 0, 1>,
                              hipFuncAttributeMaxDynamicSharedMemorySize, LDS8);
    (void)hipFuncSetAttribute((const void*)&gemm8<0, 0, 1, 1>,
                              hipFuncAttributeMaxDynamicSharedMemorySize, LDS8);

    detect_dtype<<<1, 64, 0, stream>>>((const unsigned short*)W1, flag);
    conv_bias_all<<<28, blk, 0, stream>>>(b1, b2, b3, b4, bq, bk, bv, fb, flag);
    conv_weight_t7<<<dim3(32, 32, 7), blk, 0, stream>>>(
        W1, W1t, W4, W4t, Wq, Wqt, Wk, Wkt, Wv, Wvt, W2, W2t, W3, W3t, flag);

    conv_to_bf16<<<8192, blk, 0, stream>>>(x, XC, NE, flag);

    // MLP: L1/L3/L4 on gemm8 (256x256), L2 (N=512) on proven gemm_bt
    gemm8<1, 1, 0, 1><<<dim3(4, 64), blk8, LDS8, stream>>>(
        XC, W1t, fb1, PA, Mx, 1024, 1024, 1.f, Z0, Z0, Z0, flag);
    gemm_bt<1, 1, 0, 1><<<dim3(4, 128), blk, 0, stream>>>(
        PA, W2t, fb2, PB, Mx, 512, 1024, 1.f, Z0, Z0, Z0, flag);
    gemm8<1, 1, 0, 1><<<dim3(4, 64), blk8, LDS8, stream>>>(
        PB, W3t, fb3, PA, Mx, 1024, 512, 1.f, Z0, Z0, Z0, flag);
    gemm8<1, 1, 0, 1><<<dim3(4, 64), blk8, LDS8, stream>>>(
        PA, W4t, fb4, PB, Mx, 1024, 1024, 1.f, Z0, Z0, Z0, flag);

    // q -> PA ; y -> XC ; k -> PB
    gemm8<0, 1, 0, 1><<<dim3(4, 64), blk8, LDS8, stream>>>(
        PB, Wqt, fbq, PA, Mx, 1024, 1024, 1.f, Z0, Z0, Z0, flag);
    conv_to_bf16<<<8192, blk, 0, stream>>>(y, XC, NE, flag);
    gemm8<0, 1, 0, 1><<<dim3(4, 64), blk8, LDS8, stream>>>(
        XC, Wkt, fbk, PB, Mx, 1024, 1024, 1.f, Z0, Z0, Z0, flag);

    if (direct) {
        gemm8<0, 2, 0, 0><<<dim3(8, 4, 8), blk8, LDS8, stream>>>(
            Wvt, XC, fbv, VT, 1024, 2048, 1024, 1.f, Z0, sQK, sQK, flag);
        gemm8<0, 0, 0, 1><<<dim3(8, 8, 8), blk8, LDS8, stream>>>(
            PA, PB, nullptr, SBUF, 2048, 2048, 1024, 0.03125f, sQK, sQK, sS, flag);
        softmax_rows<<<dim3(8 * 2048), blk, 0, stream>>>(SBUF, 2048);
        gemm8<0, 0, 1, 1><<<dim3(4, 8, 8), blk8, LDS8, stream>>>(
            SBUF, VT, nullptr, d_out, 2048, 1024, 2048, 1.f, sS, sQK, sQK, flag);
    } else {
        for (int g = 0; g < 8; g += G) {
            const size_t off = (size_t)g * 2048 * 1024;
            gemm_bt<0, 2, 0, 0><<<dim3(16, 8, G), blk, 0, stream>>>(
                Wvt, XC + off, fbv, VT, 1024, 2048, 1024, 1.f, Z0, sQK, sQK, flag);
            gemm_bt<0, 0, 0, 1><<<dim3(16, 16, G), blk, 0, stream>>>(
                PA + off, PB + off, nullptr, SBUF, 2048, 2048, 1024, 0.03125f, sQK, sQK, sS, flag);
            softmax_rows<<<dim3(G * 2048), blk, 0, stream>>>(SBUF, 2048);
            gemm_bt<0, 0, 0, 1><<<dim3(8, 16, G), blk, 0, stream>>>(
                SBUF, VT, nullptr, OUTS + off, 2048, 1024, 2048, 1.f, sS, sQK, sQK, flag);
        }
        write_out<<<8192, blk, 0, stream>>>(OUTS, d_out, NE, flag);
    }
}

// Round 3
// 633.824 us; speedup vs baseline: 1.2523x; 1.2523x over previous
//
#include <hip/hip_runtime.h>
#include <stdint.h>

// CrossAttention, fp32/bf16 I/O autodetect, all-bf16 MFMA pipeline.
// R8: revert R7's counted-lgkm + pinned reads (regressed). Base = R6.
// Only change vs R6: staging re-slotted so every vmcnt drain waits on
// loads issued >=3 phases earlier. A staged in row-quarters {0-63,128-191}
// (lo) / {64-127,192-255} (hi) matching RD_LO/RD_HI row usage; B staged
// whole-tile in ph3/4 (buf-B read-dead after ph2). Drains: ph1 vm(8),
// ph4 vm(4), ph8 vm(10). lgkmcnt(0) TOPs and read macros identical to R6.

typedef __attribute__((ext_vector_type(8))) short bf16x8;
typedef __attribute__((ext_vector_type(4))) float f32x4;
typedef __attribute__((ext_vector_type(8))) unsigned short u16x8;

__device__ __forceinline__ float bf2f(unsigned short u) {
    return __uint_as_float(((unsigned int)u) << 16);
}
__device__ __forceinline__ unsigned short f2bf(float f) {
    unsigned int u = __float_as_uint(f);
    unsigned int r = (u + 0x7fffu + ((u >> 16) & 1u)) >> 16;
    return (unsigned short)r;
}

__device__ __forceinline__ void async16(const void* g, void* l) {
    __builtin_amdgcn_global_load_lds(
        (const __attribute__((address_space(1))) unsigned int*)g,
        (__attribute__((address_space(3))) unsigned int*)l,
        16, 0, 0);
}

// ---------------------------------------------------------------------------
__global__ __launch_bounds__(64) void detect_dtype(
    const unsigned short* __restrict__ w, int* __restrict__ flag)
{
    const int t = threadIdx.x;
    int cnt = 0;
    for (int i = t; i < 4096; i += 64) {
        const unsigned e = (w[i] >> 7) & 0xFF;
        cnt += (e >= 140) ? 1 : 0;
    }
#pragma unroll
    for (int off = 32; off; off >>= 1) cnt += __shfl_xor(cnt, off, 64);
    if (t == 0) flag[0] = (cnt >= 8) ? 1 : 0;
}

// ---------------------------------------------------------------------------
__global__ __launch_bounds__(256) void conv_bias_all(
    const void* b1, const void* b2, const void* b3, const void* b4,
    const void* bq, const void* bk, const void* bv,
    float* __restrict__ out, const int* __restrict__ flag)
{
    const int i = blockIdx.x * 256 + threadIdx.x;
    const int slot = i >> 10, idx = i & 1023;
    if (slot == 1 && idx >= 512) return;
    const void* src = (slot == 0) ? b1 : (slot == 1) ? b2 : (slot == 2) ? b3 :
                      (slot == 3) ? b4 : (slot == 4) ? bq : (slot == 5) ? bk : bv;
    out[i] = (*flag) ? ((const float*)src)[idx]
                     : bf2f(((const unsigned short*)src)[idx]);
}

// ---------------------------------------------------------------------------
__device__ __forceinline__ void wt_body(
    const void* in, unsigned short* out, int R, int C, int f)
{
    __shared__ unsigned short tile[32][33];
    const int bc = blockIdx.x * 32;
    const int br = blockIdx.y * 32;
    const int x = threadIdx.x & 31;
    const int y = threadIdx.x >> 5;
#pragma unroll
    for (int i = 0; i < 4; i++) {
        const int r = y + i * 8;
        unsigned short v;
        if (f) v = f2bf(((const float*)in)[(size_t)(br + r) * C + bc + x]);
        else   v = ((const unsigned short*)in)[(size_t)(br + r) * C + bc + x];
        tile[r][x] = v;
    }
    __syncthreads();
#pragma unroll
    for (int i = 0; i < 4; i++) {
        const int r = y + i * 8;
        out[(size_t)(bc + r) * R + br + x] = tile[x][r];
    }
}

__global__ __launch_bounds__(256) void conv_weight_t7(
    const void* i0, unsigned short* o0, const void* i1, unsigned short* o1,
    const void* i2, unsigned short* o2, const void* i3, unsigned short* o3,
    const void* i4, unsigned short* o4, const void* i5, unsigned short* o5,
    const void* i6, unsigned short* o6, const int* flag)
{
    const int z = blockIdx.z;
    if (z == 5) {
        if (blockIdx.x >= 16) return;
        wt_body(i5, o5, 1024, 512, *flag);
        return;
    }
    if (z == 6) {
        if (blockIdx.y >= 16) return;
        wt_body(i6, o6, 512, 1024, *flag);
        return;
    }
    const void* in = (z == 0) ? i0 : (z == 1) ? i1 : (z == 2) ? i2 : (z == 3) ? i3 : i4;
    unsigned short* out = (z == 0) ? o0 : (z == 1) ? o1 : (z == 2) ? o2 : (z == 3) ? o3 : o4;
    wt_body(in, out, 1024, 1024, *flag);
}

__global__ __launch_bounds__(256) void conv_to_bf16(
    const void* __restrict__ in, unsigned short* __restrict__ out,
    int n, const int* __restrict__ flag)
{
    const int i = (blockIdx.x * 256 + threadIdx.x) * 8;
    if (i >= n) return;
    if (*flag) {
        const float4* p = (const float4*)((const float*)in + i);
        const float4 a = p[0], b = p[1];
        u16x8 o;
        o[0] = f2bf(a.x); o[1] = f2bf(a.y); o[2] = f2bf(a.z); o[3] = f2bf(a.w);
        o[4] = f2bf(b.x); o[5] = f2bf(b.y); o[6] = f2bf(b.z); o[7] = f2bf(b.w);
        *(u16x8*)(out + i) = o;
    } else {
        *(u16x8*)(out + i) = *(const u16x8*)((const unsigned short*)in + i);
    }
}

__global__ __launch_bounds__(256) void write_out(
    const unsigned short* __restrict__ src, void* __restrict__ dst,
    int n, const int* __restrict__ flag)
{
    const int i = (blockIdx.x * 256 + threadIdx.x) * 8;
    if (i >= n) return;
    const u16x8 v = *(const u16x8*)(src + i);
    if (*flag) {
        float4 a, b;
        a.x = bf2f(v[0]); a.y = bf2f(v[1]); a.z = bf2f(v[2]); a.w = bf2f(v[3]);
        b.x = bf2f(v[4]); b.y = bf2f(v[5]); b.z = bf2f(v[6]); b.w = bf2f(v[7]);
        float4* p = (float4*)((float*)dst + i);
        p[0] = a; p[1] = b;
    } else {
        *(u16x8*)((unsigned short*)dst + i) = v;
    }
}

// ---------------------------------------------------------------------------
// Proven 128x128 GEMM (R3/R4): C = act(alpha*A@B^T + bias). Kept for L2
// (N=512) and the low-workspace fallback path.
// ---------------------------------------------------------------------------
template <int RELU, int BIAS, int OUTF, int SWZ>
__global__ __launch_bounds__(256, 2) void gemm_bt(
    const unsigned short* __restrict__ A, const unsigned short* __restrict__ B,
    const float* __restrict__ bias, void* __restrict__ C,
    int M, int N, int K, float alpha,
    long long sA, long long sB, long long sC, const int* __restrict__ flag)
{
    int bxi = blockIdx.x, byi = blockIdx.y;
    if (SWZ) {
        const int id = byi * gridDim.x + bxi;
        bxi = (id >> 3) % gridDim.x;
        byi = (id >> 3) / gridDim.x * 8 + (id & 7);
    }
    const int z = blockIdx.z;
    A += (size_t)z * (size_t)sA;
    B += (size_t)z * (size_t)sB;
    const size_t cofs = (size_t)z * (size_t)sC;

    const int bm = byi * 128;
    const int bn = bxi * 128;
    const int t = threadIdx.x;
    const int lane = t & 63;
    const int w = t >> 6;
    const int wr = (w >> 1) * 64;
    const int wc = (w & 1) * 64;

    __shared__ unsigned short sAt[128 * 32];
    __shared__ unsigned short sBt[128 * 32];

    f32x4 acc[4][4];
#pragma unroll
    for (int i = 0; i < 4; i++)
#pragma unroll
        for (int j = 0; j < 4; j++)
            acc[i][j] = (f32x4){0.f, 0.f, 0.f, 0.f};

    const int tr = t >> 2;
    const int tc = (t & 3) << 3;
    const unsigned short* ga = A + (size_t)(bm + tr) * K + tc;
    const unsigned short* gb = B + (size_t)(bn + tr) * K + tc;
    unsigned short* la = &sAt[tr * 32 + tc];
    unsigned short* lb = &sBt[tr * 32 + tc];

    const int am = wr + (lane & 15);
    const int bn_ = wc + (lane & 15);
    const int ak = (lane >> 4) * 8;

    for (int k0 = 0; k0 < K; k0 += 32) {
        async16(ga, la);
        async16(ga + (size_t)64 * K, la + 64 * 32);
        async16(gb, lb);
        async16(gb + (size_t)64 * K, lb + 64 * 32);
        ga += 32;
        gb += 32;
        __syncthreads();

        bf16x8 af[4], bfr[4];
#pragma unroll
        for (int i = 0; i < 4; i++)
            af[i] = *(const bf16x8*)&sAt[(am + i * 16) * 32 + ak];
#pragma unroll
        for (int j = 0; j < 4; j++)
            bfr[j] = *(const bf16x8*)&sBt[(bn_ + j * 16) * 32 + ak];
#pragma unroll
        for (int i = 0; i < 4; i++)
#pragma unroll
            for (int j = 0; j < 4; j++)
                acc[i][j] = __builtin_amdgcn_mfma_f32_16x16x32_bf16(
                    af[i], bfr[j], acc[i][j], 0, 0, 0);
        __syncthreads();
    }

    const int fl = OUTF ? *flag : 0;
#pragma unroll
    for (int i = 0; i < 4; i++) {
        const int row0 = bm + wr + i * 16 + (lane >> 4) * 4;
#pragma unroll
        for (int j = 0; j < 4; j++) {
            const int col = bn + wc + j * 16 + (lane & 15);
            float bc = 0.f;
            if (BIAS == 1) bc = bias[col];
#pragma unroll
            for (int r = 0; r < 4; r++) {
                float bv = bc;
                if (BIAS == 2) bv = bias[row0 + r];
                float vv = acc[i][j][r] * alpha + bv;
                if (RELU) vv = fmaxf(vv, 0.f);
                const size_t idx = cofs + (size_t)(row0 + r) * N + col;
                if (OUTF && fl) ((float*)C)[idx] = vv;
                else ((unsigned short*)C)[idx] = f2bf(vv);
            }
        }
    }
}

// ---------------------------------------------------------------------------
// R8: 256x256 tile, BK=64, 8 waves (512 thr), 8-phase schedule per 2 K-tiles.
// Phase layout (iter over tile pair (T,T+1); buf0=T, buf1=T+1):
//   ph1: rd buf0 lo                               FMA  vm(8)  <- drains A(T)hi (3 ph old)
//   ph2: rd buf0 hi                               FMA
//   ph3: stage B(T+2) rows{0-63,128-191}          FMA
//   ph4: stage B(T+2) rows{64-127,192-255}        FMA  vm(4)  <- drains tile T+1 (4 ph old)
//   ph5: rd buf1 lo, stage A(T+2) lo-quarters     FMA
//   ph6: rd buf1 hi, stage A(T+2) hi-quarters     FMA
//   ph7: stage A(T+3) lo + B(T+3) h0              FMA
//   ph8: stage A(T+3) hi + B(T+3) h1              FMA  vm(10) <- drains B(T+2)+A(T+2)lo (>=3 ph old)
// Buf overwrite safety: buf0 reads complete at ph2-top (lgkm0+barrier) before
// ph3-6 writes; buf1 reads complete at ph6-top before ph7/8 writes.
// Requires M%256==0, N%256==0, K%128==0, K>=256.
// ---------------------------------------------------------------------------
#define G8_STGQ(gbase, dbase, T, q) do {                                       \
    const unsigned short* _s = (gbase) + (size_t)((q) * 64) * K                \
                                       + (size_t)(T) * 64;                     \
    unsigned short* _d = (dbase) + (((T) & 1) ? 16384 : 0) + (q) * 4096;       \
    async16(_s, _d);                                                           \
} while (0)

#define G8_RD_LO(PA_, PB_)                                                     \
    _Pragma("unroll")                                                          \
    for (int m_ = 0; m_ < 4; m_++) {                                           \
        aL[m_][0] = *(const bf16x8*)&(PA_)[rA + m_ * 1024 + c0];               \
        aL[m_][1] = *(const bf16x8*)&(PA_)[rA + m_ * 1024 + c1];               \
    }                                                                          \
    _Pragma("unroll")                                                          \
    for (int n_ = 0; n_ < 4; n_++)                                             \
        bb[n_][0] = *(const bf16x8*)&(PB_)[rB + n_ * 1024 + c0];

#define G8_RD_HI(PA_, PB_)                                                     \
    _Pragma("unroll")                                                          \
    for (int m_ = 0; m_ < 4; m_++) {                                           \
        aH[m_][0] = *(const bf16x8*)&(PA_)[rA + (m_ + 4) * 1024 + c0];         \
        aH[m_][1] = *(const bf16x8*)&(PA_)[rA + (m_ + 4) * 1024 + c1];         \
    }                                                                          \
    _Pragma("unroll")                                                          \
    for (int n_ = 0; n_ < 4; n_++)                                             \
        bb[n_][1] = *(const bf16x8*)&(PB_)[rB + n_ * 1024 + c1];

#define G8_TOP()                                                               \
    __builtin_amdgcn_s_barrier();                                              \
    asm volatile("s_waitcnt lgkmcnt(0)" ::: "memory");                         \
    __builtin_amdgcn_sched_barrier(0);                                         \
    __builtin_amdgcn_s_setprio(1);

#define G8_FMA(AF, KK, MOFS)                                                   \
    _Pragma("unroll")                                                          \
    for (int m_ = 0; m_ < 4; m_++) {                                           \
        _Pragma("unroll")                                                      \
        for (int n_ = 0; n_ < 4; n_++)                                         \
            acc[(MOFS) + m_][n_] = __builtin_amdgcn_mfma_f32_16x16x32_bf16(    \
                AF[m_][KK], bb[n_][KK], acc[(MOFS) + m_][n_], 0, 0, 0);        \
    }

#define G8_BOT()                                                               \
    __builtin_amdgcn_s_setprio(0);                                             \
    asm volatile("" ::: "memory");                                             \
    __builtin_amdgcn_s_barrier();                                              \
    asm volatile("" ::: "memory");

#define G8_BOTVM(N)                                                            \
    __builtin_amdgcn_s_setprio(0);                                             \
    asm volatile("s_waitcnt vmcnt(" #N ")" ::: "memory");                      \
    __builtin_amdgcn_s_barrier();                                              \
    asm volatile("" ::: "memory");

template <int RELU, int BIAS, int OUTF, int SWZ>
__global__ __launch_bounds__(512, 2) void gemm8(
    const unsigned short* __restrict__ A, const unsigned short* __restrict__ B,
    const float* __restrict__ bias, void* __restrict__ C,
    int M, int N, int K, float alpha,
    long long sA, long long sB, long long sC, const int* __restrict__ flag)
{
    extern __shared__ unsigned short lds[];
    (void)M;
    int bxi = blockIdx.x, byi = blockIdx.y;
    if (SWZ) {
        const int id = byi * gridDim.x + bxi;
        bxi = (id >> 3) % gridDim.x;
        byi = (id >> 3) / gridDim.x * 8 + (id & 7);
    }
    const int z = blockIdx.z;
    A += (size_t)z * (size_t)sA;
    B += (size_t)z * (size_t)sB;
    const size_t cofs = (size_t)z * (size_t)sC;

    const int bm = byi * 256;
    const int bn = bxi * 256;
    const int t = threadIdx.x;
    const int lane = t & 63;
    const int w = t >> 6;
    const int wm = w >> 2;   // 0..1  (128 output rows each)
    const int wn = w & 3;    // 0..3  (64 output cols each)

    unsigned short* LA = lds;            // [2][256][64] A panels
    unsigned short* LB = lds + 32768;    // [2][256][64] B panels

    // --- staging: linear LDS dest, inverse-swizzled global source (T2) ---
    const int rowi = t >> 3;                          // 0..63
    const int co = ((t & 7) ^ (rowi & 7)) << 3;       // swizzled k-col (elems)
    const unsigned short* gA = A + (size_t)(bm + rowi) * K + co;
    const unsigned short* gB = B + (size_t)(bn + rowi) * K + co;
    unsigned short* dA = LA + t * 8;
    unsigned short* dB = LB + t * 8;

    // --- swizzled ds_read offsets (halfs) ---
    const int rA = (wm * 128 + (lane & 15)) * 64;
    const int rB = (wn * 64 + (lane & 15)) * 64;
    const int swz = (lane & 7) << 4;                  // byte swizzle
    const int c0 = ((((lane >> 4) << 4)) ^ swz) >> 1; // k0 slice, halfs
    const int c1 = ((64 | ((lane >> 4) << 4)) ^ swz) >> 1; // k1 slice

    f32x4 acc[8][4];
#pragma unroll
    for (int i = 0; i < 8; i++)
#pragma unroll
        for (int j = 0; j < 4; j++)
            acc[i][j] = (f32x4){0.f, 0.f, 0.f, 0.f};

    bf16x8 aL[4][2], aH[4][2], bb[4][2];

    // prologue: tile0 fully (8), tile1 in ph7/ph8 order (a1 lo+b1 h0, a1 hi+b1 h1);
    // drain tile0 only (vm(8) leaves tile1's 8 outstanding).
    G8_STGQ(gA, dA, 0, 0); G8_STGQ(gA, dA, 0, 2);
    G8_STGQ(gA, dA, 0, 1); G8_STGQ(gA, dA, 0, 3);
    G8_STGQ(gB, dB, 0, 0); G8_STGQ(gB, dB, 0, 1);
    G8_STGQ(gB, dB, 0, 2); G8_STGQ(gB, dB, 0, 3);
    G8_STGQ(gA, dA, 1, 0); G8_STGQ(gA, dA, 1, 2);
    G8_STGQ(gB, dB, 1, 0); G8_STGQ(gB, dB, 1, 1);
    G8_STGQ(gA, dA, 1, 1); G8_STGQ(gA, dA, 1, 3);
    G8_STGQ(gB, dB, 1, 2); G8_STGQ(gB, dB, 1, 3);
    asm volatile("s_waitcnt vmcnt(8)" ::: "memory");
    __builtin_amdgcn_s_barrier();
    asm volatile("" ::: "memory");

    const int NI = K >> 7;   // iterations, 2 K-tiles (of 64) each
    int kt = 0;
    for (int i = 0; i < NI - 1; ++i, kt += 2) {
        // ph1: read buf0 lo ; drain A(T)hi (issued 3 phases back)
        G8_RD_LO(LA, LB)
        G8_TOP()
        G8_FMA(aL, 0, 0)
        G8_BOTVM(8)
        // ph2: read buf0 hi
        G8_RD_HI(LA, LB)
        G8_TOP()
        G8_FMA(aL, 1, 0)
        G8_BOT()
        // ph3: stage B(T+2) rows {0-63,128-191}  (buf0-B read-dead)
        G8_STGQ(gB, dB, kt + 2, 0);
        G8_STGQ(gB, dB, kt + 2, 2);
        G8_TOP()
        G8_FMA(aH, 0, 4)
        G8_BOT()
        // ph4: stage B(T+2) rows {64-127,192-255} ; drain tile T+1 (4 ph back)
        G8_STGQ(gB, dB, kt + 2, 1);
        G8_STGQ(gB, dB, kt + 2, 3);
        G8_TOP()
        G8_FMA(aH, 1, 4)
        G8_BOTVM(4)
        // ph5: read buf1 lo ; stage A(T+2) lo-quarters
        G8_RD_LO((LA + 16384), (LB + 16384))
        G8_STGQ(gA, dA, kt + 2, 0);
        G8_STGQ(gA, dA, kt + 2, 2);
        G8_TOP()
        G8_FMA(aL, 0, 0)
        G8_BOT()
        // ph6: read buf1 hi ; stage A(T+2) hi-quarters
        G8_RD_HI((LA + 16384), (LB + 16384))
        G8_STGQ(gA, dA, kt + 2, 1);
        G8_STGQ(gA, dA, kt + 2, 3);
        G8_TOP()
        G8_FMA(aL, 1, 0)
        G8_BOT()
        // ph7: stage A(T+3) lo + B(T+3) h0 (buf1 read-dead since ph6-top)
        G8_STGQ(gA, dA, kt + 3, 0);
        G8_STGQ(gA, dA, kt + 3, 2);
        G8_STGQ(gB, dB, kt + 3, 0);
        G8_STGQ(gB, dB, kt + 3, 1);
        G8_TOP()
        G8_FMA(aH, 0, 4)
        G8_BOT()
        // ph8: stage A(T+3) hi + B(T+3) h1 ; drain B(T+2)+A(T+2)lo (>=3 ph back)
        G8_STGQ(gA, dA, kt + 3, 1);
        G8_STGQ(gA, dA, kt + 3, 3);
        G8_STGQ(gB, dB, kt + 3, 2);
        G8_STGQ(gB, dB, kt + 3, 3);
        G8_TOP()
        G8_FMA(aH, 1, 4)
        G8_BOTVM(10)
    }
    // final iteration: tiles kt (buf0), kt+1 (buf1); no staging.
    {
        G8_RD_LO(LA, LB)
        G8_TOP()
        G8_FMA(aL, 0, 0)
        G8_BOTVM(8)            // drains A(kt)hi staged in prev iter ph6
        G8_RD_HI(LA, LB)
        G8_TOP()
        G8_FMA(aL, 1, 0)
        G8_BOT()
        G8_TOP()
        G8_FMA(aH, 0, 4)
        G8_BOT()
        G8_TOP()
        G8_FMA(aH, 1, 4)
        G8_BOTVM(0)            // tile kt+1 fully resident
        G8_RD_LO((LA + 16384), (LB + 16384))
        G8_TOP()
        G8_FMA(aL, 0, 0)
        G8_BOT()
        G8_RD_HI((LA + 16384), (LB + 16384))
        G8_TOP()
        G8_FMA(aL, 1, 0)
        G8_BOT()
        G8_TOP()
        G8_FMA(aH, 0, 4)
        G8_BOT()
        G8_TOP()
        G8_FMA(aH, 1, 4)
        __builtin_amdgcn_s_setprio(0);
    }

    const int fl = OUTF ? *flag : 0;
#pragma unroll
    for (int mi = 0; mi < 8; mi++) {
        const int row0 = bm + wm * 128 + mi * 16 + (lane >> 4) * 4;
#pragma unroll
        for (int n = 0; n < 4; n++) {
            const int col = bn + wn * 64 + n * 16 + (lane & 15);
            float bc = 0.f;
            if (BIAS == 1) bc = bias[col];
#pragma unroll
            for (int r = 0; r < 4; r++) {
                float bv = bc;
                if (BIAS == 2) bv = bias[row0 + r];
                float vv = acc[mi][n][r] * alpha + bv;
                if (RELU) vv = fmaxf(vv, 0.f);
                const size_t idx = cofs + (size_t)(row0 + r) * N + col;
                if (OUTF && fl) ((float*)C)[idx] = vv;
                else ((unsigned short*)C)[idx] = f2bf(vv);
            }
        }
    }
}

// ---------------------------------------------------------------------------
__global__ __launch_bounds__(256) void softmax_rows(unsigned short* S, int n)
{
    const size_t row = blockIdx.x;
    unsigned short* p = S + row * (size_t)n;
    const int t = threadIdx.x;
    const int lane = t & 63;
    const int wave = t >> 6;

    u16x8 v = *(const u16x8*)(p + t * 8);
    float f[8];
    float m = -3.0e38f;
#pragma unroll
    for (int i = 0; i < 8; i++) {
        f[i] = bf2f(v[i]);
        m = fmaxf(m, f[i]);
    }
#pragma unroll
    for (int off = 32; off; off >>= 1) m = fmaxf(m, __shfl_xor(m, off, 64));
    __shared__ float redm[4];
    if (lane == 0) redm[wave] = m;
    __syncthreads();
    m = fmaxf(fmaxf(redm[0], redm[1]), fmaxf(redm[2], redm[3]));

    float e[8];
    float s = 0.f;
#pragma unroll
    for (int i = 0; i < 8; i++) {
        e[i] = __expf(f[i] - m);
        s += e[i];
    }
#pragma unroll
    for (int off = 32; off; off >>= 1) s += __shfl_xor(s, off, 64);
    __shared__ float reds[4];
    if (lane == 0) reds[wave] = s;
    __syncthreads();
    s = reds[0] + reds[1] + reds[2] + reds[3];
    const float inv = 1.0f / s;

    u16x8 o;
#pragma unroll
    for (int i = 0; i < 8; i++) o[i] = f2bf(e[i] * inv);
    *(u16x8*)(p + t * 8) = o;
}

// ---------------------------------------------------------------------------
extern "C" void kernel_launch(void* const* d_in, const int* in_sizes, int n_in,
                              void* d_out, int out_size, void* d_ws, size_t ws_size,
                              hipStream_t stream)
{
    const void* x  = d_in[0];
    const void* y  = d_in[1];
    const void* W1 = d_in[2];
    const void* b1 = d_in[3];
    const void* W2 = d_in[4];
    const void* b2 = d_in[5];
    const void* W3 = d_in[6];
    const void* b3 = d_in[7];
    const void* W4 = d_in[8];
    const void* b4 = d_in[9];
    const void* Wq = d_in[10];
    const void* bq = d_in[11];
    const void* Wk = d_in[12];
    const void* bk = d_in[13];
    const void* Wv = d_in[14];
    const void* bv = d_in[15];

    int* flag = (int*)d_ws;
    float* fb = (float*)((char*)d_ws + 64);
    unsigned short* arena = (unsigned short*)((char*)d_ws + 64 + 7 * 1024 * 4);
    const size_t baseB = 64 + 7 * 1024 * 4;
    const size_t MEG = 1024ull * 1024ull;

    auto needB = [&](int G, bool direct) -> size_t {
        return baseB + 2ull * ((6 + 16 + (size_t)G * 6 + (direct ? 0 : 16)) * MEG);
    };
    int G; bool direct;
    if (ws_size >= needB(8, true))      { G = 8; direct = true;  }
    else if (ws_size >= needB(4, false)) { G = 4; direct = false; }
    else if (ws_size >= needB(2, false)) { G = 2; direct = false; }
    else                                 { G = 1; direct = false; }

    unsigned short* W1t = arena;
    unsigned short* W2t = W1t + 1 * MEG;
    unsigned short* W3t = W2t + MEG / 2;
    unsigned short* W4t = W3t + MEG / 2;
    unsigned short* Wqt = W4t + 1 * MEG;
    unsigned short* Wkt = Wqt + 1 * MEG;
    unsigned short* Wvt = Wkt + 1 * MEG;
    unsigned short* XC  = Wvt + 1 * MEG;
    unsigned short* VT  = XC + 16 * MEG;
    unsigned short* SBUF = VT + (size_t)G * 2 * MEG;
    unsigned short* OUTS = SBUF + (size_t)G * 4 * MEG;

    unsigned short* PA = (unsigned short*)d_out;
    unsigned short* PB = PA + 16 * MEG;

    float* fb1 = fb;
    float* fb2 = fb + 1024;
    float* fb3 = fb + 2048;
    float* fb4 = fb + 3072;
    float* fbq = fb + 4096;
    float* fbk = fb + 5120;
    float* fbv = fb + 6144;

    const dim3 blk(256);
    const dim3 blk8(512);
    const int LDS8 = 131072;
    const int NE = 16 * 1024 * 1024;
    const int Mx = 16384;
    const long long Z0 = 0;
    const long long sQK = 2048ll * 1024;
    const long long sS  = 2048ll * 2048;

    // allow 128 KiB dynamic LDS for every gemm8 instantiation we launch
    (void)hipFuncSetAttribute((const void*)&gemm8<1, 1, 0, 1>,
                              hipFuncAttributeMaxDynamicSharedMemorySize, LDS8);
    (void)hipFuncSetAttribute((const void*)&gemm8<0, 1, 0, 1>,
                              hipFuncAttributeMaxDynamicSharedMemorySize, LDS8);
    (void)hipFuncSetAttribute((const void*)&gemm8<0, 2, 0, 0>,
                              hipFuncAttributeMaxDynamicSharedMemorySize, LDS8);
    (void)hipFuncSetAttribute((const void*)&gemm8<0, 0, 0, 1>,
                              hipFuncAttributeMaxDynamicSharedMemorySize, LDS8);
    (void)hipFuncSetAttribute((const void*)&gemm8<0, 0, 1, 1>,
                              hipFuncAttributeMaxDynamicSharedMemorySize, LDS8);

    detect_dtype<<<1, 64, 0, stream>>>((const unsigned short*)W1, flag);
    conv_bias_all<<<28, blk, 0, stream>>>(b1, b2, b3, b4, bq, bk, bv, fb, flag);
    conv_weight_t7<<<dim3(32, 32, 7), blk, 0, stream>>>(
        W1, W1t, W4, W4t, Wq, Wqt, Wk, Wkt, Wv, Wvt, W2, W2t, W3, W3t, flag);

    conv_to_bf16<<<8192, blk, 0, stream>>>(x, XC, NE, flag);

    // MLP: L1/L3/L4 on gemm8 (256x256), L2 (N=512) on proven gemm_bt
    gemm8<1, 1, 0, 1><<<dim3(4, 64), blk8, LDS8, stream>>>(
        XC, W1t, fb1, PA, Mx, 1024, 1024, 1.f, Z0, Z0, Z0, flag);
    gemm_bt<1, 1, 0, 1><<<dim3(4, 128), blk, 0, stream>>>(
        PA, W2t, fb2, PB, Mx, 512, 1024, 1.f, Z0, Z0, Z0, flag);
    gemm8<1, 1, 0, 1><<<dim3(4, 64), blk8, LDS8, stream>>>(
        PB, W3t, fb3, PA, Mx, 1024, 512, 1.f, Z0, Z0, Z0, flag);
    gemm8<1, 1, 0, 1><<<dim3(4, 64), blk8, LDS8, stream>>>(
        PA, W4t, fb4, PB, Mx, 1024, 1024, 1.f, Z0, Z0, Z0, flag);

    // q -> PA ; y -> XC ; k -> PB
    gemm8<0, 1, 0, 1><<<dim3(4, 64), blk8, LDS8, stream>>>(
        PB, Wqt, fbq, PA, Mx, 1024, 1024, 1.f, Z0, Z0, Z0, flag);
    conv_to_bf16<<<8192, blk, 0, stream>>>(y, XC, NE, flag);
    gemm8<0, 1, 0, 1><<<dim3(4, 64), blk8, LDS8, stream>>>(
        XC, Wkt, fbk, PB, Mx, 1024, 1024, 1.f, Z0, Z0, Z0, flag);

    if (direct) {
        gemm8<0, 2, 0, 0><<<dim3(8, 4, 8), blk8, LDS8, stream>>>(
            Wvt, XC, fbv, VT, 1024, 2048, 1024, 1.f, Z0, sQK, sQK, flag);
        gemm8<0, 0, 0, 1><<<dim3(8, 8, 8), blk8, LDS8, stream>>>(
            PA, PB, nullptr, SBUF, 2048, 2048, 1024, 0.03125f, sQK, sQK, sS, flag);
        softmax_rows<<<dim3(8 * 2048), blk, 0, stream>>>(SBUF, 2048);
        gemm8<0, 0, 1, 1><<<dim3(4, 8, 8), blk8, LDS8, stream>>>(
            SBUF, VT, nullptr, d_out, 2048, 1024, 2048, 1.f, sS, sQK, sQK, flag);
    } else {
        for (int g = 0; g < 8; g += G) {
            const size_t off = (size_t)g * 2048 * 1024;
            gemm_bt<0, 2, 0, 0><<<dim3(16, 8, G), blk, 0, stream>>>(
                Wvt, XC + off, fbv, VT, 1024, 2048, 1024, 1.f, Z0, sQK, sQK, flag);
            gemm_bt<0, 0, 0, 1><<<dim3(16, 16, G), blk, 0, stream>>>(
                PA + off, PB + off, nullptr, SBUF, 2048, 2048, 1024, 0.03125f, sQK, sQK, sS, flag);
            softmax_rows<<<dim3(G * 2048), blk, 0, stream>>>(SBUF, 2048);
            gemm_bt<0, 0, 0, 1><<<dim3(8, 16, G), blk, 0, stream>>>(
                SBUF, VT, nullptr, OUTS + off, 2048, 1024, 2048, 1.f, sS, sQK, sQK, flag);
        }
        write_out<<<8192, blk, 0, stream>>>(OUTS, d_out, NE, flag);
    }
}

// Round 4
// 617.398 us; speedup vs baseline: 1.2856x; 1.0266x over previous
//
#include <hip/hip_runtime.h>
#include <stdint.h>

// CrossAttention, fp32/bf16 I/O autodetect, all-bf16 MFMA pipeline.
// R9: gemm8 restructured — BK=32, 4 LDS tile-slots, ds_reads lead their
// consuming MFMA phase by ONE phase with counted lgkmcnt(4/8) (the m218
// counted-wait principle applied to the LDS side), staging issued
// post-barrier into just-freed slots (lgkm-before-barrier makes this
// WAR-safe), vmcnt(10) drains only >=6-phase-old loads. Conflict-free
// XOR swizzle across 128-B super-rows. gemm_bt kept for L2 + fallback.

typedef __attribute__((ext_vector_type(8))) short bf16x8;
typedef __attribute__((ext_vector_type(4))) float f32x4;
typedef __attribute__((ext_vector_type(8))) unsigned short u16x8;

__device__ __forceinline__ float bf2f(unsigned short u) {
    return __uint_as_float(((unsigned int)u) << 16);
}
__device__ __forceinline__ unsigned short f2bf(float f) {
    unsigned int u = __float_as_uint(f);
    unsigned int r = (u + 0x7fffu + ((u >> 16) & 1u)) >> 16;
    return (unsigned short)r;
}

__device__ __forceinline__ void async16(const void* g, void* l) {
    __builtin_amdgcn_global_load_lds(
        (const __attribute__((address_space(1))) unsigned int*)g,
        (__attribute__((address_space(3))) unsigned int*)l,
        16, 0, 0);
}

// ---------------------------------------------------------------------------
__global__ __launch_bounds__(64) void detect_dtype(
    const unsigned short* __restrict__ w, int* __restrict__ flag)
{
    const int t = threadIdx.x;
    int cnt = 0;
    for (int i = t; i < 4096; i += 64) {
        const unsigned e = (w[i] >> 7) & 0xFF;
        cnt += (e >= 140) ? 1 : 0;
    }
#pragma unroll
    for (int off = 32; off; off >>= 1) cnt += __shfl_xor(cnt, off, 64);
    if (t == 0) flag[0] = (cnt >= 8) ? 1 : 0;
}

// ---------------------------------------------------------------------------
__global__ __launch_bounds__(256) void conv_bias_all(
    const void* b1, const void* b2, const void* b3, const void* b4,
    const void* bq, const void* bk, const void* bv,
    float* __restrict__ out, const int* __restrict__ flag)
{
    const int i = blockIdx.x * 256 + threadIdx.x;
    const int slot = i >> 10, idx = i & 1023;
    if (slot == 1 && idx >= 512) return;
    const void* src = (slot == 0) ? b1 : (slot == 1) ? b2 : (slot == 2) ? b3 :
                      (slot == 3) ? b4 : (slot == 4) ? bq : (slot == 5) ? bk : bv;
    out[i] = (*flag) ? ((const float*)src)[idx]
                     : bf2f(((const unsigned short*)src)[idx]);
}

// ---------------------------------------------------------------------------
__device__ __forceinline__ void wt_body(
    const void* in, unsigned short* out, int R, int C, int f)
{
    __shared__ unsigned short tile[32][33];
    const int bc = blockIdx.x * 32;
    const int br = blockIdx.y * 32;
    const int x = threadIdx.x & 31;
    const int y = threadIdx.x >> 5;
#pragma unroll
    for (int i = 0; i < 4; i++) {
        const int r = y + i * 8;
        unsigned short v;
        if (f) v = f2bf(((const float*)in)[(size_t)(br + r) * C + bc + x]);
        else   v = ((const unsigned short*)in)[(size_t)(br + r) * C + bc + x];
        tile[r][x] = v;
    }
    __syncthreads();
#pragma unroll
    for (int i = 0; i < 4; i++) {
        const int r = y + i * 8;
        out[(size_t)(bc + r) * R + br + x] = tile[x][r];
    }
}

__global__ __launch_bounds__(256) void conv_weight_t7(
    const void* i0, unsigned short* o0, const void* i1, unsigned short* o1,
    const void* i2, unsigned short* o2, const void* i3, unsigned short* o3,
    const void* i4, unsigned short* o4, const void* i5, unsigned short* o5,
    const void* i6, unsigned short* o6, const int* flag)
{
    const int z = blockIdx.z;
    if (z == 5) {
        if (blockIdx.x >= 16) return;
        wt_body(i5, o5, 1024, 512, *flag);
        return;
    }
    if (z == 6) {
        if (blockIdx.y >= 16) return;
        wt_body(i6, o6, 512, 1024, *flag);
        return;
    }
    const void* in = (z == 0) ? i0 : (z == 1) ? i1 : (z == 2) ? i2 : (z == 3) ? i3 : i4;
    unsigned short* out = (z == 0) ? o0 : (z == 1) ? o1 : (z == 2) ? o2 : (z == 3) ? o3 : o4;
    wt_body(in, out, 1024, 1024, *flag);
}

__global__ __launch_bounds__(256) void conv_to_bf16(
    const void* __restrict__ in, unsigned short* __restrict__ out,
    int n, const int* __restrict__ flag)
{
    const int i = (blockIdx.x * 256 + threadIdx.x) * 8;
    if (i >= n) return;
    if (*flag) {
        const float4* p = (const float4*)((const float*)in + i);
        const float4 a = p[0], b = p[1];
        u16x8 o;
        o[0] = f2bf(a.x); o[1] = f2bf(a.y); o[2] = f2bf(a.z); o[3] = f2bf(a.w);
        o[4] = f2bf(b.x); o[5] = f2bf(b.y); o[6] = f2bf(b.z); o[7] = f2bf(b.w);
        *(u16x8*)(out + i) = o;
    } else {
        *(u16x8*)(out + i) = *(const u16x8*)((const unsigned short*)in + i);
    }
}

__global__ __launch_bounds__(256) void write_out(
    const unsigned short* __restrict__ src, void* __restrict__ dst,
    int n, const int* __restrict__ flag)
{
    const int i = (blockIdx.x * 256 + threadIdx.x) * 8;
    if (i >= n) return;
    const u16x8 v = *(const u16x8*)(src + i);
    if (*flag) {
        float4 a, b;
        a.x = bf2f(v[0]); a.y = bf2f(v[1]); a.z = bf2f(v[2]); a.w = bf2f(v[3]);
        b.x = bf2f(v[4]); b.y = bf2f(v[5]); b.z = bf2f(v[6]); b.w = bf2f(v[7]);
        float4* p = (float4*)((float*)dst + i);
        p[0] = a; p[1] = b;
    } else {
        *(u16x8*)((unsigned short*)dst + i) = v;
    }
}

// ---------------------------------------------------------------------------
// Proven 128x128 GEMM (R3/R4): C = act(alpha*A@B^T + bias). Kept for L2
// (N=512) and the low-workspace fallback path.
// ---------------------------------------------------------------------------
template <int RELU, int BIAS, int OUTF, int SWZ>
__global__ __launch_bounds__(256, 2) void gemm_bt(
    const unsigned short* __restrict__ A, const unsigned short* __restrict__ B,
    const float* __restrict__ bias, void* __restrict__ C,
    int M, int N, int K, float alpha,
    long long sA, long long sB, long long sC, const int* __restrict__ flag)
{
    int bxi = blockIdx.x, byi = blockIdx.y;
    if (SWZ) {
        const int id = byi * gridDim.x + bxi;
        bxi = (id >> 3) % gridDim.x;
        byi = (id >> 3) / gridDim.x * 8 + (id & 7);
    }
    const int z = blockIdx.z;
    A += (size_t)z * (size_t)sA;
    B += (size_t)z * (size_t)sB;
    const size_t cofs = (size_t)z * (size_t)sC;

    const int bm = byi * 128;
    const int bn = bxi * 128;
    const int t = threadIdx.x;
    const int lane = t & 63;
    const int w = t >> 6;
    const int wr = (w >> 1) * 64;
    const int wc = (w & 1) * 64;

    __shared__ unsigned short sAt[128 * 32];
    __shared__ unsigned short sBt[128 * 32];

    f32x4 acc[4][4];
#pragma unroll
    for (int i = 0; i < 4; i++)
#pragma unroll
        for (int j = 0; j < 4; j++)
            acc[i][j] = (f32x4){0.f, 0.f, 0.f, 0.f};

    const int tr = t >> 2;
    const int tc = (t & 3) << 3;
    const unsigned short* ga = A + (size_t)(bm + tr) * K + tc;
    const unsigned short* gb = B + (size_t)(bn + tr) * K + tc;
    unsigned short* la = &sAt[tr * 32 + tc];
    unsigned short* lb = &sBt[tr * 32 + tc];

    const int am = wr + (lane & 15);
    const int bn_ = wc + (lane & 15);
    const int ak = (lane >> 4) * 8;

    for (int k0 = 0; k0 < K; k0 += 32) {
        async16(ga, la);
        async16(ga + (size_t)64 * K, la + 64 * 32);
        async16(gb, lb);
        async16(gb + (size_t)64 * K, lb + 64 * 32);
        ga += 32;
        gb += 32;
        __syncthreads();

        bf16x8 af[4], bfr[4];
#pragma unroll
        for (int i = 0; i < 4; i++)
            af[i] = *(const bf16x8*)&sAt[(am + i * 16) * 32 + ak];
#pragma unroll
        for (int j = 0; j < 4; j++)
            bfr[j] = *(const bf16x8*)&sBt[(bn_ + j * 16) * 32 + ak];
#pragma unroll
        for (int i = 0; i < 4; i++)
#pragma unroll
            for (int j = 0; j < 4; j++)
                acc[i][j] = __builtin_amdgcn_mfma_f32_16x16x32_bf16(
                    af[i], bfr[j], acc[i][j], 0, 0, 0);
        __syncthreads();
    }

    const int fl = OUTF ? *flag : 0;
#pragma unroll
    for (int i = 0; i < 4; i++) {
        const int row0 = bm + wr + i * 16 + (lane >> 4) * 4;
#pragma unroll
        for (int j = 0; j < 4; j++) {
            const int col = bn + wc + j * 16 + (lane & 15);
            float bc = 0.f;
            if (BIAS == 1) bc = bias[col];
#pragma unroll
            for (int r = 0; r < 4; r++) {
                float bv = bc;
                if (BIAS == 2) bv = bias[row0 + r];
                float vv = acc[i][j][r] * alpha + bv;
                if (RELU) vv = fmaxf(vv, 0.f);
                const size_t idx = cofs + (size_t)(row0 + r) * N + col;
                if (OUTF && fl) ((float*)C)[idx] = vv;
                else ((unsigned short*)C)[idx] = f2bf(vv);
            }
        }
    }
}

// ---------------------------------------------------------------------------
// R9 gemm8: 256x256 tile, BK=32, 8 waves, 4 LDS tile-slots of 32 KiB
// (A[4][256x32] then B[4][256x32], 128 KiB total). 4 phases per 64-K pair:
//   phN body: [issue NEXT phase's read-group] [lgkm(cnt) ; barrier ;
//             sched_barrier ; setprio(1)] [stage into just-freed slot]
//             [16 MFMA] [setprio(0) ; (vmcnt) ; barrier]
// Read groups: G1={aEl,bbE}(8) G2={aEh}(4) G3={aOl,bbO}(8) G4={aOh}(4);
// G(p+1) issued in phase p -> lgkm(4|8) waits only the 1-phase-old group.
// Staging sigma1..4 = B(te''),A(te''),B(to''),A(to'') for pair i+2, written
// in place of pair i's slots AFTER the lgkm+barrier that retires their last
// reader. Drains vmcnt(10) at ph1/ph3 wait only >=6-phase-old loads.
// Requires M%256==0, N%256==0, K%64==0, K>=256.
// ---------------------------------------------------------------------------
#define G9_STG(gs, d, e, T) do {                                               \
    const unsigned short* _s = (gs) + (size_t)(int)(T) * 32;                   \
    unsigned short* _d = (d) + (e) * 8192;                                     \
    async16(_s, _d);                                                           \
    async16(_s + rk128, _d + 4096);                                            \
} while (0)

#define G9_RD8(AX, BX, PA_, PB_)                                               \
    _Pragma("unroll")                                                          \
    for (int m_ = 0; m_ < 4; m_++)                                             \
        AX[m_] = *(const bf16x8*)((PA_) + m_ * 512);                           \
    _Pragma("unroll")                                                          \
    for (int n_ = 0; n_ < 4; n_++)                                             \
        BX[n_] = *(const bf16x8*)((PB_) + n_ * 512);

#define G9_RD4(AX, PA_)                                                        \
    _Pragma("unroll")                                                          \
    for (int m_ = 0; m_ < 4; m_++)                                             \
        AX[m_] = *(const bf16x8*)((PA_) + (m_ + 4) * 512);

#define G9_TOPL_I(LG)                                                          \
    asm volatile("s_waitcnt lgkmcnt(" #LG ")" ::: "memory");                   \
    __builtin_amdgcn_s_barrier();                                              \
    __builtin_amdgcn_sched_barrier(0);                                         \
    __builtin_amdgcn_s_setprio(1);
#define G9_TOPL(LG) G9_TOPL_I(LG)

#define G9_FMA(AF, BF, MOFS)                                                   \
    _Pragma("unroll")                                                          \
    for (int m_ = 0; m_ < 4; m_++) {                                           \
        _Pragma("unroll")                                                      \
        for (int n_ = 0; n_ < 4; n_++)                                         \
            acc[(MOFS) + m_][n_] = __builtin_amdgcn_mfma_f32_16x16x32_bf16(    \
                AF[m_], BF[n_], acc[(MOFS) + m_][n_], 0, 0, 0);                \
    }

#define G9_BOTP()                                                              \
    __builtin_amdgcn_s_setprio(0);                                             \
    asm volatile("" ::: "memory");                                             \
    __builtin_amdgcn_s_barrier();                                              \
    asm volatile("" ::: "memory");

#define G9_BOTV_I(N)                                                           \
    __builtin_amdgcn_s_setprio(0);                                             \
    asm volatile("s_waitcnt vmcnt(" #N ")" ::: "memory");                      \
    __builtin_amdgcn_s_barrier();                                              \
    asm volatile("" ::: "memory");
#define G9_BOTV(N) G9_BOTV_I(N)

// One 64-K pair (4 phases). PAE/PBE = even-tile slot ptrs, PAO/PBO = odd,
// PAN/PBN = next pair's even slot (for the G1' read). EE/EO = slot indices
// being restaged; TE/TO = staged tile indices. SG = stage?, V1/V3 = vmcnt.
#define G9_ITER(PAE, PBE, PAO, PBO, PAN, PBN, EE, EO, TE, TO, SG, V1, V3)      \
    G9_RD4(aEh, PAE)                                                           \
    G9_TOPL(4)                                                                 \
    if (SG) G9_STG(gBs, dB, EE, TE);                                           \
    G9_FMA(aEl, bbE, 0)                                                        \
    G9_BOTV(V1)                                                                \
    G9_RD8(aOl, bbO, PAO, PBO)                                                 \
    G9_TOPL(8)                                                                 \
    if (SG) G9_STG(gAs, dA, EE, TE);                                           \
    G9_FMA(aEh, bbE, 4)                                                        \
    G9_BOTP()                                                                  \
    G9_RD4(aOh, PAO)                                                           \
    G9_TOPL(4)                                                                 \
    if (SG) G9_STG(gBs, dB, EO, TO);                                           \
    G9_FMA(aOl, bbO, 0)                                                        \
    G9_BOTV(V3)                                                                \
    G9_RD8(aEl, bbE, PAN, PBN)                                                 \
    G9_TOPL(8)                                                                 \
    if (SG) G9_STG(gAs, dA, EO, TO);                                           \
    G9_FMA(aOh, bbO, 4)                                                        \
    G9_BOTP()

template <int RELU, int BIAS, int OUTF, int SWZ>
__global__ __launch_bounds__(512, 2) void gemm8(
    const unsigned short* __restrict__ A, const unsigned short* __restrict__ B,
    const float* __restrict__ bias, void* __restrict__ C,
    int M, int N, int K, float alpha,
    long long sA, long long sB, long long sC, const int* __restrict__ flag)
{
    extern __shared__ unsigned short lds[];
    (void)M;
    int bxi = blockIdx.x, byi = blockIdx.y;
    if (SWZ) {
        const int id = byi * gridDim.x + bxi;
        bxi = (id >> 3) % gridDim.x;
        byi = (id >> 3) / gridDim.x * 8 + (id & 7);
    }
    const int z = blockIdx.z;
    A += (size_t)z * (size_t)sA;
    B += (size_t)z * (size_t)sB;
    const size_t cofs = (size_t)z * (size_t)sC;

    const int bm = byi * 256;
    const int bn = bxi * 256;
    const int t = threadIdx.x;
    const int lane = t & 63;
    const int w = t >> 6;
    const int wm = w >> 2;   // 0..1  (128 output rows each)
    const int wn = w & 3;    // 0..3  (64 output cols each)

    // --- staging: linear LDS dest; source pre-inverse-swizzled (st_16x32
    // style: 16-B granule (R,s) holds row 2R+(u>>2), octet u&3, u=s^(R&7)).
    const int u0 = (t & 7) ^ ((t >> 3) & 7);
    const int srow = 2 * (t >> 3) + (u0 >> 2);
    const int soct = (u0 & 3) << 3;
    const unsigned short* gAs = A + (size_t)(bm + srow) * K + soct;
    const unsigned short* gBs = B + (size_t)(bn + srow) * K + soct;
    const size_t rk128 = (size_t)128 * K;
    unsigned short* dA = lds + t * 8;
    unsigned short* dB = lds + 32768 + t * 8;

    // --- swizzled ds_read bases (ushort units within a slot) ---
    const int l15 = lane & 15;
    const int xs = ((((lane >> 4) | ((lane & 1) << 2)) ^ (l15 >> 1)) << 3);
    const int abase = (wm * 64 + (l15 >> 1)) * 64 + xs;
    const int bbase = (wn * 32 + (l15 >> 1)) * 64 + xs;
    const unsigned short* pA0 = lds + abase;
    const unsigned short* pA1 = lds + 8192 + abase;
    const unsigned short* pA2 = lds + 16384 + abase;
    const unsigned short* pA3 = lds + 24576 + abase;
    const unsigned short* pB0 = lds + 32768 + bbase;
    const unsigned short* pB1 = lds + 40960 + bbase;
    const unsigned short* pB2 = lds + 49152 + bbase;
    const unsigned short* pB3 = lds + 57344 + bbase;

    f32x4 acc[8][4];
#pragma unroll
    for (int i = 0; i < 8; i++)
#pragma unroll
        for (int j = 0; j < 4; j++)
            acc[i][j] = (f32x4){0.f, 0.f, 0.f, 0.f};

    bf16x8 aEl[4], aEh[4], aOl[4], aOh[4], bbE[4], bbO[4];

    // prologue: tiles 0..3 -> slots 0..3, sigma order B,A per tile.
    G9_STG(gBs, dB, 0, 0); G9_STG(gAs, dA, 0, 0);
    G9_STG(gBs, dB, 1, 1); G9_STG(gAs, dA, 1, 1);
    G9_STG(gBs, dB, 2, 2); G9_STG(gAs, dA, 2, 2);
    G9_STG(gBs, dB, 3, 3); G9_STG(gAs, dA, 3, 3);
    asm volatile("s_waitcnt vmcnt(12)" ::: "memory");
    __builtin_amdgcn_s_barrier();
    asm volatile("" ::: "memory");
    G9_RD8(aEl, bbE, pA0, pB0)           // G1 of pair 0

    const int NI = K >> 6;               // pairs of 32-K tiles
    int ts = 4;                          // first staged tile index
    for (int p = 0; p <= NI - 4; p += 2) {
        G9_ITER(pA0, pB0, pA1, pB1, pA2, pB2, 0, 1, ts,     ts + 1, 1, 10, 10)
        G9_ITER(pA2, pB2, pA3, pB3, pA0, pB0, 2, 3, ts + 2, ts + 3, 1, 10, 10)
        ts += 4;
    }
    // tail1: pair NI-2 (slots 0,1), no staging; still issues G1' (slots 2,3).
    G9_ITER(pA0, pB0, pA1, pB1, pA2, pB2, 0, 1, 0, 0, 0, 8, 4)
    // tail2: pair NI-1 (slots 2,3), last — no G1', no staging.
    G9_RD4(aEh, pA2)
    G9_TOPL(4)
    G9_FMA(aEl, bbE, 0)
    G9_BOTV(0)
    G9_RD8(aOl, bbO, pA3, pB3)
    G9_TOPL(8)
    G9_FMA(aEh, bbE, 4)
    G9_BOTP()
    G9_RD4(aOh, pA3)
    G9_TOPL(4)
    G9_FMA(aOl, bbO, 0)
    G9_BOTV(0)
    G9_TOPL(0)
    G9_FMA(aOh, bbO, 4)
    __builtin_amdgcn_s_setprio(0);

    const int fl = OUTF ? *flag : 0;
#pragma unroll
    for (int mi = 0; mi < 8; mi++) {
        const int row0 = bm + wm * 128 + mi * 16 + (lane >> 4) * 4;
#pragma unroll
        for (int n = 0; n < 4; n++) {
            const int col = bn + wn * 64 + n * 16 + (lane & 15);
            float bc = 0.f;
            if (BIAS == 1) bc = bias[col];
#pragma unroll
            for (int r = 0; r < 4; r++) {
                float bv = bc;
                if (BIAS == 2) bv = bias[row0 + r];
                float vv = acc[mi][n][r] * alpha + bv;
                if (RELU) vv = fmaxf(vv, 0.f);
                const size_t idx = cofs + (size_t)(row0 + r) * N + col;
                if (OUTF && fl) ((float*)C)[idx] = vv;
                else ((unsigned short*)C)[idx] = f2bf(vv);
            }
        }
    }
}

// ---------------------------------------------------------------------------
__global__ __launch_bounds__(256) void softmax_rows(unsigned short* S, int n)
{
    const size_t row = blockIdx.x;
    unsigned short* p = S + row * (size_t)n;
    const int t = threadIdx.x;
    const int lane = t & 63;
    const int wave = t >> 6;

    u16x8 v = *(const u16x8*)(p + t * 8);
    float f[8];
    float m = -3.0e38f;
#pragma unroll
    for (int i = 0; i < 8; i++) {
        f[i] = bf2f(v[i]);
        m = fmaxf(m, f[i]);
    }
#pragma unroll
    for (int off = 32; off; off >>= 1) m = fmaxf(m, __shfl_xor(m, off, 64));
    __shared__ float redm[4];
    if (lane == 0) redm[wave] = m;
    __syncthreads();
    m = fmaxf(fmaxf(redm[0], redm[1]), fmaxf(redm[2], redm[3]));

    float e[8];
    float s = 0.f;
#pragma unroll
    for (int i = 0; i < 8; i++) {
        e[i] = __expf(f[i] - m);
        s += e[i];
    }
#pragma unroll
    for (int off = 32; off; off >>= 1) s += __shfl_xor(s, off, 64);
    __shared__ float reds[4];
    if (lane == 0) reds[wave] = s;
    __syncthreads();
    s = reds[0] + reds[1] + reds[2] + reds[3];
    const float inv = 1.0f / s;

    u16x8 o;
#pragma unroll
    for (int i = 0; i < 8; i++) o[i] = f2bf(e[i] * inv);
    *(u16x8*)(p + t * 8) = o;
}

// ---------------------------------------------------------------------------
extern "C" void kernel_launch(void* const* d_in, const int* in_sizes, int n_in,
                              void* d_out, int out_size, void* d_ws, size_t ws_size,
                              hipStream_t stream)
{
    const void* x  = d_in[0];
    const void* y  = d_in[1];
    const void* W1 = d_in[2];
    const void* b1 = d_in[3];
    const void* W2 = d_in[4];
    const void* b2 = d_in[5];
    const void* W3 = d_in[6];
    const void* b3 = d_in[7];
    const void* W4 = d_in[8];
    const void* b4 = d_in[9];
    const void* Wq = d_in[10];
    const void* bq = d_in[11];
    const void* Wk = d_in[12];
    const void* bk = d_in[13];
    const void* Wv = d_in[14];
    const void* bv = d_in[15];

    int* flag = (int*)d_ws;
    float* fb = (float*)((char*)d_ws + 64);
    unsigned short* arena = (unsigned short*)((char*)d_ws + 64 + 7 * 1024 * 4);
    const size_t baseB = 64 + 7 * 1024 * 4;
    const size_t MEG = 1024ull * 1024ull;

    auto needB = [&](int G, bool direct) -> size_t {
        return baseB + 2ull * ((6 + 16 + (size_t)G * 6 + (direct ? 0 : 16)) * MEG);
    };
    int G; bool direct;
    if (ws_size >= needB(8, true))      { G = 8; direct = true;  }
    else if (ws_size >= needB(4, false)) { G = 4; direct = false; }
    else if (ws_size >= needB(2, false)) { G = 2; direct = false; }
    else                                 { G = 1; direct = false; }

    unsigned short* W1t = arena;
    unsigned short* W2t = W1t + 1 * MEG;
    unsigned short* W3t = W2t + MEG / 2;
    unsigned short* W4t = W3t + MEG / 2;
    unsigned short* Wqt = W4t + 1 * MEG;
    unsigned short* Wkt = Wqt + 1 * MEG;
    unsigned short* Wvt = Wkt + 1 * MEG;
    unsigned short* XC  = Wvt + 1 * MEG;
    unsigned short* VT  = XC + 16 * MEG;
    unsigned short* SBUF = VT + (size_t)G * 2 * MEG;
    unsigned short* OUTS = SBUF + (size_t)G * 4 * MEG;

    unsigned short* PA = (unsigned short*)d_out;
    unsigned short* PB = PA + 16 * MEG;

    float* fb1 = fb;
    float* fb2 = fb + 1024;
    float* fb3 = fb + 2048;
    float* fb4 = fb + 3072;
    float* fbq = fb + 4096;
    float* fbk = fb + 5120;
    float* fbv = fb + 6144;

    const dim3 blk(256);
    const dim3 blk8(512);
    const int LDS8 = 131072;
    const int NE = 16 * 1024 * 1024;
    const int Mx = 16384;
    const long long Z0 = 0;
    const long long sQK = 2048ll * 1024;
    const long long sS  = 2048ll * 2048;

    // allow 128 KiB dynamic LDS for every gemm8 instantiation we launch
    (void)hipFuncSetAttribute((const void*)&gemm8<1, 1, 0, 1>,
                              hipFuncAttributeMaxDynamicSharedMemorySize, LDS8);
    (void)hipFuncSetAttribute((const void*)&gemm8<0, 1, 0, 1>,
                              hipFuncAttributeMaxDynamicSharedMemorySize, LDS8);
    (void)hipFuncSetAttribute((const void*)&gemm8<0, 2, 0, 0>,
                              hipFuncAttributeMaxDynamicSharedMemorySize, LDS8);
    (void)hipFuncSetAttribute((const void*)&gemm8<0, 0, 0, 1>,
                              hipFuncAttributeMaxDynamicSharedMemorySize, LDS8);
    (void)hipFuncSetAttribute((const void*)&gemm8<0, 0, 1, 1>,
                              hipFuncAttributeMaxDynamicSharedMemorySize, LDS8);

    detect_dtype<<<1, 64, 0, stream>>>((const unsigned short*)W1, flag);
    conv_bias_all<<<28, blk, 0, stream>>>(b1, b2, b3, b4, bq, bk, bv, fb, flag);
    conv_weight_t7<<<dim3(32, 32, 7), blk, 0, stream>>>(
        W1, W1t, W4, W4t, Wq, Wqt, Wk, Wkt, Wv, Wvt, W2, W2t, W3, W3t, flag);

    conv_to_bf16<<<8192, blk, 0, stream>>>(x, XC, NE, flag);

    // MLP: L1/L3/L4 on gemm8 (256x256), L2 (N=512) on proven gemm_bt
    gemm8<1, 1, 0, 1><<<dim3(4, 64), blk8, LDS8, stream>>>(
        XC, W1t, fb1, PA, Mx, 1024, 1024, 1.f, Z0, Z0, Z0, flag);
    gemm_bt<1, 1, 0, 1><<<dim3(4, 128), blk, 0, stream>>>(
        PA, W2t, fb2, PB, Mx, 512, 1024, 1.f, Z0, Z0, Z0, flag);
    gemm8<1, 1, 0, 1><<<dim3(4, 64), blk8, LDS8, stream>>>(
        PB, W3t, fb3, PA, Mx, 1024, 512, 1.f, Z0, Z0, Z0, flag);
    gemm8<1, 1, 0, 1><<<dim3(4, 64), blk8, LDS8, stream>>>(
        PA, W4t, fb4, PB, Mx, 1024, 1024, 1.f, Z0, Z0, Z0, flag);

    // q -> PA ; y -> XC ; k -> PB
    gemm8<0, 1, 0, 1><<<dim3(4, 64), blk8, LDS8, stream>>>(
        PB, Wqt, fbq, PA, Mx, 1024, 1024, 1.f, Z0, Z0, Z0, flag);
    conv_to_bf16<<<8192, blk, 0, stream>>>(y, XC, NE, flag);
    gemm8<0, 1, 0, 1><<<dim3(4, 64), blk8, LDS8, stream>>>(
        XC, Wkt, fbk, PB, Mx, 1024, 1024, 1.f, Z0, Z0, Z0, flag);

    if (direct) {
        gemm8<0, 2, 0, 0><<<dim3(8, 4, 8), blk8, LDS8, stream>>>(
            Wvt, XC, fbv, VT, 1024, 2048, 1024, 1.f, Z0, sQK, sQK, flag);
        gemm8<0, 0, 0, 1><<<dim3(8, 8, 8), blk8, LDS8, stream>>>(
            PA, PB, nullptr, SBUF, 2048, 2048, 1024, 0.03125f, sQK, sQK, sS, flag);
        softmax_rows<<<dim3(8 * 2048), blk, 0, stream>>>(SBUF, 2048);
        gemm8<0, 0, 1, 1><<<dim3(4, 8, 8), blk8, LDS8, stream>>>(
            SBUF, VT, nullptr, d_out, 2048, 1024, 2048, 1.f, sS, sQK, sQK, flag);
    } else {
        for (int g = 0; g < 8; g += G) {
            const size_t off = (size_t)g * 2048 * 1024;
            gemm_bt<0, 2, 0, 0><<<dim3(16, 8, G), blk, 0, stream>>>(
                Wvt, XC + off, fbv, VT, 1024, 2048, 1024, 1.f, Z0, sQK, sQK, flag);
            gemm_bt<0, 0, 0, 1><<<dim3(16, 16, G), blk, 0, stream>>>(
                PA + off, PB + off, nullptr, SBUF, 2048, 2048, 1024, 0.03125f, sQK, sQK, sS, flag);
            softmax_rows<<<dim3(G * 2048), blk, 0, stream>>>(SBUF, 2048);
            gemm_bt<0, 0, 0, 1><<<dim3(8, 16, G), blk, 0, stream>>>(
                SBUF, VT, nullptr, OUTS + off, 2048, 1024, 2048, 1.f, sS, sQK, sQK, flag);
        }
        write_out<<<8192, blk, 0, stream>>>(OUTS, d_out, NE, flag);
    }
}

// Round 5
// 602.935 us; speedup vs baseline: 1.3164x; 1.0240x over previous
//
#include <hip/hip_runtime.h>
#include <stdint.h>

// CrossAttention, fp32/bf16 I/O autodetect, all-bf16 MFMA pipeline.
// R10: gemm8 rebuilt around barrier-count reduction. Evidence R6-R9: phase
// time pinned ~1425cy under ANY read/stage slotting -> barrier/lockstep
// overhead (16 s_barrier per 2-K-tiles, ~400cy each, 1 block/CU) dominates.
// New structure: BK=32, 4 LDS tile-slots (4x32KiB), ONE phase per K-tile =
// {stage tile T+2 (4 loads) | 12 ds_read | 32 MFMA | vmcnt(4) | barrier}.
// 1 barrier + 1 vmcnt per K-tile (4x fewer). End-of-phase vmcnt-before-
// barrier guarantees all-wave residency of tile T+1. 2-way-free swizzle
// for 64B rows: oct ^= (lane>>1)&3 (lanes 0-7 tile all 32 banks).
// gemm_bt kept for L2 (N=512) + fallback path.

typedef __attribute__((ext_vector_type(8))) short bf16x8;
typedef __attribute__((ext_vector_type(4))) float f32x4;
typedef __attribute__((ext_vector_type(8))) unsigned short u16x8;

__device__ __forceinline__ float bf2f(unsigned short u) {
    return __uint_as_float(((unsigned int)u) << 16);
}
__device__ __forceinline__ unsigned short f2bf(float f) {
    unsigned int u = __float_as_uint(f);
    unsigned int r = (u + 0x7fffu + ((u >> 16) & 1u)) >> 16;
    return (unsigned short)r;
}

__device__ __forceinline__ void async16(const void* g, void* l) {
    __builtin_amdgcn_global_load_lds(
        (const __attribute__((address_space(1))) unsigned int*)g,
        (__attribute__((address_space(3))) unsigned int*)l,
        16, 0, 0);
}

// ---------------------------------------------------------------------------
__global__ __launch_bounds__(64) void detect_dtype(
    const unsigned short* __restrict__ w, int* __restrict__ flag)
{
    const int t = threadIdx.x;
    int cnt = 0;
    for (int i = t; i < 4096; i += 64) {
        const unsigned e = (w[i] >> 7) & 0xFF;
        cnt += (e >= 140) ? 1 : 0;
    }
#pragma unroll
    for (int off = 32; off; off >>= 1) cnt += __shfl_xor(cnt, off, 64);
    if (t == 0) flag[0] = (cnt >= 8) ? 1 : 0;
}

// ---------------------------------------------------------------------------
__global__ __launch_bounds__(256) void conv_bias_all(
    const void* b1, const void* b2, const void* b3, const void* b4,
    const void* bq, const void* bk, const void* bv,
    float* __restrict__ out, const int* __restrict__ flag)
{
    const int i = blockIdx.x * 256 + threadIdx.x;
    const int slot = i >> 10, idx = i & 1023;
    if (slot == 1 && idx >= 512) return;
    const void* src = (slot == 0) ? b1 : (slot == 1) ? b2 : (slot == 2) ? b3 :
                      (slot == 3) ? b4 : (slot == 4) ? bq : (slot == 5) ? bk : bv;
    out[i] = (*flag) ? ((const float*)src)[idx]
                     : bf2f(((const unsigned short*)src)[idx]);
}

// ---------------------------------------------------------------------------
__device__ __forceinline__ void wt_body(
    const void* in, unsigned short* out, int R, int C, int f)
{
    __shared__ unsigned short tile[32][33];
    const int bc = blockIdx.x * 32;
    const int br = blockIdx.y * 32;
    const int x = threadIdx.x & 31;
    const int y = threadIdx.x >> 5;
#pragma unroll
    for (int i = 0; i < 4; i++) {
        const int r = y + i * 8;
        unsigned short v;
        if (f) v = f2bf(((const float*)in)[(size_t)(br + r) * C + bc + x]);
        else   v = ((const unsigned short*)in)[(size_t)(br + r) * C + bc + x];
        tile[r][x] = v;
    }
    __syncthreads();
#pragma unroll
    for (int i = 0; i < 4; i++) {
        const int r = y + i * 8;
        out[(size_t)(bc + r) * R + br + x] = tile[x][r];
    }
}

__global__ __launch_bounds__(256) void conv_weight_t7(
    const void* i0, unsigned short* o0, const void* i1, unsigned short* o1,
    const void* i2, unsigned short* o2, const void* i3, unsigned short* o3,
    const void* i4, unsigned short* o4, const void* i5, unsigned short* o5,
    const void* i6, unsigned short* o6, const int* flag)
{
    const int z = blockIdx.z;
    if (z == 5) {
        if (blockIdx.x >= 16) return;
        wt_body(i5, o5, 1024, 512, *flag);
        return;
    }
    if (z == 6) {
        if (blockIdx.y >= 16) return;
        wt_body(i6, o6, 512, 1024, *flag);
        return;
    }
    const void* in = (z == 0) ? i0 : (z == 1) ? i1 : (z == 2) ? i2 : (z == 3) ? i3 : i4;
    unsigned short* out = (z == 0) ? o0 : (z == 1) ? o1 : (z == 2) ? o2 : (z == 3) ? o3 : o4;
    wt_body(in, out, 1024, 1024, *flag);
}

__global__ __launch_bounds__(256) void conv_to_bf16(
    const void* __restrict__ in, unsigned short* __restrict__ out,
    int n, const int* __restrict__ flag)
{
    const int i = (blockIdx.x * 256 + threadIdx.x) * 8;
    if (i >= n) return;
    if (*flag) {
        const float4* p = (const float4*)((const float*)in + i);
        const float4 a = p[0], b = p[1];
        u16x8 o;
        o[0] = f2bf(a.x); o[1] = f2bf(a.y); o[2] = f2bf(a.z); o[3] = f2bf(a.w);
        o[4] = f2bf(b.x); o[5] = f2bf(b.y); o[6] = f2bf(b.z); o[7] = f2bf(b.w);
        *(u16x8*)(out + i) = o;
    } else {
        *(u16x8*)(out + i) = *(const u16x8*)((const unsigned short*)in + i);
    }
}

__global__ __launch_bounds__(256) void write_out(
    const unsigned short* __restrict__ src, void* __restrict__ dst,
    int n, const int* __restrict__ flag)
{
    const int i = (blockIdx.x * 256 + threadIdx.x) * 8;
    if (i >= n) return;
    const u16x8 v = *(const u16x8*)(src + i);
    if (*flag) {
        float4 a, b;
        a.x = bf2f(v[0]); a.y = bf2f(v[1]); a.z = bf2f(v[2]); a.w = bf2f(v[3]);
        b.x = bf2f(v[4]); b.y = bf2f(v[5]); b.z = bf2f(v[6]); b.w = bf2f(v[7]);
        float4* p = (float4*)((float*)dst + i);
        p[0] = a; p[1] = b;
    } else {
        *(u16x8*)((unsigned short*)dst + i) = v;
    }
}

// ---------------------------------------------------------------------------
// Proven 128x128 GEMM (R3/R4): C = act(alpha*A@B^T + bias). Kept for L2
// (N=512) and the low-workspace fallback path.
// ---------------------------------------------------------------------------
template <int RELU, int BIAS, int OUTF, int SWZ>
__global__ __launch_bounds__(256, 2) void gemm_bt(
    const unsigned short* __restrict__ A, const unsigned short* __restrict__ B,
    const float* __restrict__ bias, void* __restrict__ C,
    int M, int N, int K, float alpha,
    long long sA, long long sB, long long sC, const int* __restrict__ flag)
{
    int bxi = blockIdx.x, byi = blockIdx.y;
    if (SWZ) {
        const int id = byi * gridDim.x + bxi;
        bxi = (id >> 3) % gridDim.x;
        byi = (id >> 3) / gridDim.x * 8 + (id & 7);
    }
    const int z = blockIdx.z;
    A += (size_t)z * (size_t)sA;
    B += (size_t)z * (size_t)sB;
    const size_t cofs = (size_t)z * (size_t)sC;

    const int bm = byi * 128;
    const int bn = bxi * 128;
    const int t = threadIdx.x;
    const int lane = t & 63;
    const int w = t >> 6;
    const int wr = (w >> 1) * 64;
    const int wc = (w & 1) * 64;

    __shared__ unsigned short sAt[128 * 32];
    __shared__ unsigned short sBt[128 * 32];

    f32x4 acc[4][4];
#pragma unroll
    for (int i = 0; i < 4; i++)
#pragma unroll
        for (int j = 0; j < 4; j++)
            acc[i][j] = (f32x4){0.f, 0.f, 0.f, 0.f};

    const int tr = t >> 2;
    const int tc = (t & 3) << 3;
    const unsigned short* ga = A + (size_t)(bm + tr) * K + tc;
    const unsigned short* gb = B + (size_t)(bn + tr) * K + tc;
    unsigned short* la = &sAt[tr * 32 + tc];
    unsigned short* lb = &sBt[tr * 32 + tc];

    const int am = wr + (lane & 15);
    const int bn_ = wc + (lane & 15);
    const int ak = (lane >> 4) * 8;

    for (int k0 = 0; k0 < K; k0 += 32) {
        async16(ga, la);
        async16(ga + (size_t)64 * K, la + 64 * 32);
        async16(gb, lb);
        async16(gb + (size_t)64 * K, lb + 64 * 32);
        ga += 32;
        gb += 32;
        __syncthreads();

        bf16x8 af[4], bfr[4];
#pragma unroll
        for (int i = 0; i < 4; i++)
            af[i] = *(const bf16x8*)&sAt[(am + i * 16) * 32 + ak];
#pragma unroll
        for (int j = 0; j < 4; j++)
            bfr[j] = *(const bf16x8*)&sBt[(bn_ + j * 16) * 32 + ak];
#pragma unroll
        for (int i = 0; i < 4; i++)
#pragma unroll
            for (int j = 0; j < 4; j++)
                acc[i][j] = __builtin_amdgcn_mfma_f32_16x16x32_bf16(
                    af[i], bfr[j], acc[i][j], 0, 0, 0);
        __syncthreads();
    }

    const int fl = OUTF ? *flag : 0;
#pragma unroll
    for (int i = 0; i < 4; i++) {
        const int row0 = bm + wr + i * 16 + (lane >> 4) * 4;
#pragma unroll
        for (int j = 0; j < 4; j++) {
            const int col = bn + wc + j * 16 + (lane & 15);
            float bc = 0.f;
            if (BIAS == 1) bc = bias[col];
#pragma unroll
            for (int r = 0; r < 4; r++) {
                float bv = bc;
                if (BIAS == 2) bv = bias[row0 + r];
                float vv = acc[i][j][r] * alpha + bv;
                if (RELU) vv = fmaxf(vv, 0.f);
                const size_t idx = cofs + (size_t)(row0 + r) * N + col;
                if (OUTF && fl) ((float*)C)[idx] = vv;
                else ((unsigned short*)C)[idx] = f2bf(vv);
            }
        }
    }
}

// ---------------------------------------------------------------------------
// R10 gemm8: 256x256 tile, BK=32, 8 waves, 4 LDS tile-slots of 32 KiB
// (A slots at 0..64KiB, B slots at 64..128KiB). One phase per 32-K tile:
//   stage tile T+2 -> slot (T+2)&3   (slot last read 2 barriers ago: safe)
//   12 ds_read_b128 from slot T&3    (tile T residency: see below)
//   32 MFMA (compiler-scheduled lgkm interleave)
//   vmcnt(4) [drain own tile-T+1 loads] ; s_barrier
// The per-wave vmcnt BEFORE the barrier makes tile T+1 resident for ALL
// waves after the barrier (each wave drained its own 4 loads). 1 barrier +
// 1 vmcnt per K-tile vs 4+4 in the R6 structure.
// Swizzle (64B rows): element octet e stored at LDS octet e^((row>>1)&3);
// read addr oct = ((lane>>4)^((lane>>1)&3))*8 -> lanes 0-7 tile all 32
// banks (uniform 8-pass b128, conflict-free). Staging: linear LDS dest,
// source octet (t&3)^((t>>3)&3) (same involution).
// Requires M%256==0, N%256==0, K%32==0, K>=64.
// ---------------------------------------------------------------------------
#define G10_STG(SOFS, KOFS) do {                                               \
    async16(gAs + (KOFS), dA + (SOFS));                                        \
    async16(gAs + (KOFS) + rk128, dA + (SOFS) + 4096);                         \
    async16(gBs + (KOFS), dB + (SOFS));                                        \
    async16(gBs + (KOFS) + rk128, dB + (SOFS) + 4096);                         \
} while (0)

template <int RELU, int BIAS, int OUTF, int SWZ>
__global__ __launch_bounds__(512, 2) void gemm8(
    const unsigned short* __restrict__ A, const unsigned short* __restrict__ B,
    const float* __restrict__ bias, void* __restrict__ C,
    int M, int N, int K, float alpha,
    long long sA, long long sB, long long sC, const int* __restrict__ flag)
{
    extern __shared__ unsigned short lds[];
    (void)M;
    int bxi = blockIdx.x, byi = blockIdx.y;
    if (SWZ) {
        const int id = byi * gridDim.x + bxi;
        bxi = (id >> 3) % gridDim.x;
        byi = (id >> 3) / gridDim.x * 8 + (id & 7);
    }
    const int z = blockIdx.z;
    A += (size_t)z * (size_t)sA;
    B += (size_t)z * (size_t)sB;
    const size_t cofs = (size_t)z * (size_t)sC;

    const int bm = byi * 256;
    const int bn = bxi * 256;
    const int t = threadIdx.x;
    const int lane = t & 63;
    const int w = t >> 6;
    const int wm = w >> 2;   // 0..1  (128 output rows each)
    const int wn = w & 3;    // 0..3  (64 output cols each)

    // --- staging: linear LDS dest, inverse-swizzled global source ---
    const int soct = ((t & 3) ^ ((t >> 3) & 3)) << 3;     // element octet*8
    const unsigned short* gAs = A + (size_t)(bm + (t >> 2)) * K + soct;
    const unsigned short* gBs = B + (size_t)(bn + (t >> 2)) * K + soct;
    const size_t rk128 = (size_t)128 * K;
    unsigned short* dA = lds + t * 8;            // A slots: lds + slot*8192
    unsigned short* dB = lds + 32768 + t * 8;    // B slots: +32768

    // --- swizzled ds_read offsets (halves within a slot) ---
    const int l15 = lane & 15;
    const int oct = (((lane >> 4) ^ ((lane >> 1) & 3)) << 3);
    const int aoff = (wm * 128 + l15) * 32 + oct;
    const int boff = (wn * 64 + l15) * 32 + oct;

    f32x4 acc[8][4];
#pragma unroll
    for (int i = 0; i < 8; i++)
#pragma unroll
        for (int j = 0; j < 4; j++)
            acc[i][j] = (f32x4){0.f, 0.f, 0.f, 0.f};

    // prologue: tiles 0,1 -> slots 0,1; drain tile0 for all waves.
    G10_STG(0, 0);
    G10_STG(8192, 32);
    asm volatile("s_waitcnt vmcnt(4)" ::: "memory");
    __builtin_amdgcn_s_barrier();
    asm volatile("" ::: "memory");

    const int NT = K >> 5;
    for (int T = 0; T < NT; ++T) {
        if (T + 2 < NT) {
            const int so = ((T + 2) & 3) * 8192;
            const int ko = (T + 2) << 5;
            G10_STG(so, ko);
        }
        const int sr = (T & 3) * 8192;
        const unsigned short* pa = lds + sr + aoff;
        const unsigned short* pb = lds + 32768 + sr + boff;
        bf16x8 bb[4], a[8];
#pragma unroll
        for (int n = 0; n < 4; n++)
            bb[n] = *(const bf16x8*)(pb + n * 512);
#pragma unroll
        for (int m = 0; m < 8; m++)
            a[m] = *(const bf16x8*)(pa + m * 512);
        __builtin_amdgcn_s_setprio(1);
#pragma unroll
        for (int m = 0; m < 8; m++)
#pragma unroll
            for (int n = 0; n < 4; n++)
                acc[m][n] = __builtin_amdgcn_mfma_f32_16x16x32_bf16(
                    a[m], bb[n], acc[m][n], 0, 0, 0);
        __builtin_amdgcn_s_setprio(0);
        if (T + 1 < NT) {
            if (T + 2 < NT) {
                asm volatile("s_waitcnt vmcnt(4)" ::: "memory");
            } else {
                asm volatile("s_waitcnt vmcnt(0)" ::: "memory");
            }
            __builtin_amdgcn_s_barrier();
            asm volatile("" ::: "memory");
        }
    }

    const int fl = OUTF ? *flag : 0;
#pragma unroll
    for (int mi = 0; mi < 8; mi++) {
        const int row0 = bm + wm * 128 + mi * 16 + (lane >> 4) * 4;
#pragma unroll
        for (int n = 0; n < 4; n++) {
            const int col = bn + wn * 64 + n * 16 + (lane & 15);
            float bc = 0.f;
            if (BIAS == 1) bc = bias[col];
#pragma unroll
            for (int r = 0; r < 4; r++) {
                float bv = bc;
                if (BIAS == 2) bv = bias[row0 + r];
                float vv = acc[mi][n][r] * alpha + bv;
                if (RELU) vv = fmaxf(vv, 0.f);
                const size_t idx = cofs + (size_t)(row0 + r) * N + col;
                if (OUTF && fl) ((float*)C)[idx] = vv;
                else ((unsigned short*)C)[idx] = f2bf(vv);
            }
        }
    }
}

// ---------------------------------------------------------------------------
__global__ __launch_bounds__(256) void softmax_rows(unsigned short* S, int n)
{
    const size_t row = blockIdx.x;
    unsigned short* p = S + row * (size_t)n;
    const int t = threadIdx.x;
    const int lane = t & 63;
    const int wave = t >> 6;

    u16x8 v = *(const u16x8*)(p + t * 8);
    float f[8];
    float m = -3.0e38f;
#pragma unroll
    for (int i = 0; i < 8; i++) {
        f[i] = bf2f(v[i]);
        m = fmaxf(m, f[i]);
    }
#pragma unroll
    for (int off = 32; off; off >>= 1) m = fmaxf(m, __shfl_xor(m, off, 64));
    __shared__ float redm[4];
    if (lane == 0) redm[wave] = m;
    __syncthreads();
    m = fmaxf(fmaxf(redm[0], redm[1]), fmaxf(redm[2], redm[3]));

    float e[8];
    float s = 0.f;
#pragma unroll
    for (int i = 0; i < 8; i++) {
        e[i] = __expf(f[i] - m);
        s += e[i];
    }
#pragma unroll
    for (int off = 32; off; off >>= 1) s += __shfl_xor(s, off, 64);
    __shared__ float reds[4];
    if (lane == 0) reds[wave] = s;
    __syncthreads();
    s = reds[0] + reds[1] + reds[2] + reds[3];
    const float inv = 1.0f / s;

    u16x8 o;
#pragma unroll
    for (int i = 0; i < 8; i++) o[i] = f2bf(e[i] * inv);
    *(u16x8*)(p + t * 8) = o;
}

// ---------------------------------------------------------------------------
extern "C" void kernel_launch(void* const* d_in, const int* in_sizes, int n_in,
                              void* d_out, int out_size, void* d_ws, size_t ws_size,
                              hipStream_t stream)
{
    const void* x  = d_in[0];
    const void* y  = d_in[1];
    const void* W1 = d_in[2];
    const void* b1 = d_in[3];
    const void* W2 = d_in[4];
    const void* b2 = d_in[5];
    const void* W3 = d_in[6];
    const void* b3 = d_in[7];
    const void* W4 = d_in[8];
    const void* b4 = d_in[9];
    const void* Wq = d_in[10];
    const void* bq = d_in[11];
    const void* Wk = d_in[12];
    const void* bk = d_in[13];
    const void* Wv = d_in[14];
    const void* bv = d_in[15];

    int* flag = (int*)d_ws;
    float* fb = (float*)((char*)d_ws + 64);
    unsigned short* arena = (unsigned short*)((char*)d_ws + 64 + 7 * 1024 * 4);
    const size_t baseB = 64 + 7 * 1024 * 4;
    const size_t MEG = 1024ull * 1024ull;

    auto needB = [&](int G, bool direct) -> size_t {
        return baseB + 2ull * ((6 + 16 + (size_t)G * 6 + (direct ? 0 : 16)) * MEG);
    };
    int G; bool direct;
    if (ws_size >= needB(8, true))      { G = 8; direct = true;  }
    else if (ws_size >= needB(4, false)) { G = 4; direct = false; }
    else if (ws_size >= needB(2, false)) { G = 2; direct = false; }
    else                                 { G = 1; direct = false; }

    unsigned short* W1t = arena;
    unsigned short* W2t = W1t + 1 * MEG;
    unsigned short* W3t = W2t + MEG / 2;
    unsigned short* W4t = W3t + MEG / 2;
    unsigned short* Wqt = W4t + 1 * MEG;
    unsigned short* Wkt = Wqt + 1 * MEG;
    unsigned short* Wvt = Wkt + 1 * MEG;
    unsigned short* XC  = Wvt + 1 * MEG;
    unsigned short* VT  = XC + 16 * MEG;
    unsigned short* SBUF = VT + (size_t)G * 2 * MEG;
    unsigned short* OUTS = SBUF + (size_t)G * 4 * MEG;

    unsigned short* PA = (unsigned short*)d_out;
    unsigned short* PB = PA + 16 * MEG;

    float* fb1 = fb;
    float* fb2 = fb + 1024;
    float* fb3 = fb + 2048;
    float* fb4 = fb + 3072;
    float* fbq = fb + 4096;
    float* fbk = fb + 5120;
    float* fbv = fb + 6144;

    const dim3 blk(256);
    const dim3 blk8(512);
    const int LDS8 = 131072;
    const int NE = 16 * 1024 * 1024;
    const int Mx = 16384;
    const long long Z0 = 0;
    const long long sQK = 2048ll * 1024;
    const long long sS  = 2048ll * 2048;

    // allow 128 KiB dynamic LDS for every gemm8 instantiation we launch
    (void)hipFuncSetAttribute((const void*)&gemm8<1, 1, 0, 1>,
                              hipFuncAttributeMaxDynamicSharedMemorySize, LDS8);
    (void)hipFuncSetAttribute((const void*)&gemm8<0, 1, 0, 1>,
                              hipFuncAttributeMaxDynamicSharedMemorySize, LDS8);
    (void)hipFuncSetAttribute((const void*)&gemm8<0, 2, 0, 0>,
                              hipFuncAttributeMaxDynamicSharedMemorySize, LDS8);
    (void)hipFuncSetAttribute((const void*)&gemm8<0, 0, 0, 1>,
                              hipFuncAttributeMaxDynamicSharedMemorySize, LDS8);
    (void)hipFuncSetAttribute((const void*)&gemm8<0, 0, 1, 1>,
                              hipFuncAttributeMaxDynamicSharedMemorySize, LDS8);

    detect_dtype<<<1, 64, 0, stream>>>((const unsigned short*)W1, flag);
    conv_bias_all<<<28, blk, 0, stream>>>(b1, b2, b3, b4, bq, bk, bv, fb, flag);
    conv_weight_t7<<<dim3(32, 32, 7), blk, 0, stream>>>(
        W1, W1t, W4, W4t, Wq, Wqt, Wk, Wkt, Wv, Wvt, W2, W2t, W3, W3t, flag);

    conv_to_bf16<<<8192, blk, 0, stream>>>(x, XC, NE, flag);

    // MLP: L1/L3/L4 on gemm8 (256x256), L2 (N=512) on proven gemm_bt
    gemm8<1, 1, 0, 1><<<dim3(4, 64), blk8, LDS8, stream>>>(
        XC, W1t, fb1, PA, Mx, 1024, 1024, 1.f, Z0, Z0, Z0, flag);
    gemm_bt<1, 1, 0, 1><<<dim3(4, 128), blk, 0, stream>>>(
        PA, W2t, fb2, PB, Mx, 512, 1024, 1.f, Z0, Z0, Z0, flag);
    gemm8<1, 1, 0, 1><<<dim3(4, 64), blk8, LDS8, stream>>>(
        PB, W3t, fb3, PA, Mx, 1024, 512, 1.f, Z0, Z0, Z0, flag);
    gemm8<1, 1, 0, 1><<<dim3(4, 64), blk8, LDS8, stream>>>(
        PA, W4t, fb4, PB, Mx, 1024, 1024, 1.f, Z0, Z0, Z0, flag);

    // q -> PA ; y -> XC ; k -> PB
    gemm8<0, 1, 0, 1><<<dim3(4, 64), blk8, LDS8, stream>>>(
        PB, Wqt, fbq, PA, Mx, 1024, 1024, 1.f, Z0, Z0, Z0, flag);
    conv_to_bf16<<<8192, blk, 0, stream>>>(y, XC, NE, flag);
    gemm8<0, 1, 0, 1><<<dim3(4, 64), blk8, LDS8, stream>>>(
        XC, Wkt, fbk, PB, Mx, 1024, 1024, 1.f, Z0, Z0, Z0, flag);

    if (direct) {
        gemm8<0, 2, 0, 0><<<dim3(8, 4, 8), blk8, LDS8, stream>>>(
            Wvt, XC, fbv, VT, 1024, 2048, 1024, 1.f, Z0, sQK, sQK, flag);
        gemm8<0, 0, 0, 1><<<dim3(8, 8, 8), blk8, LDS8, stream>>>(
            PA, PB, nullptr, SBUF, 2048, 2048, 1024, 0.03125f, sQK, sQK, sS, flag);
        softmax_rows<<<dim3(8 * 2048), blk, 0, stream>>>(SBUF, 2048);
        gemm8<0, 0, 1, 1><<<dim3(4, 8, 8), blk8, LDS8, stream>>>(
            SBUF, VT, nullptr, d_out, 2048, 1024, 2048, 1.f, sS, sQK, sQK, flag);
    } else {
        for (int g = 0; g < 8; g += G) {
            const size_t off = (size_t)g * 2048 * 1024;
            gemm_bt<0, 2, 0, 0><<<dim3(16, 8, G), blk, 0, stream>>>(
                Wvt, XC + off, fbv, VT, 1024, 2048, 1024, 1.f, Z0, sQK, sQK, flag);
            gemm_bt<0, 0, 0, 1><<<dim3(16, 16, G), blk, 0, stream>>>(
                PA + off, PB + off, nullptr, SBUF, 2048, 2048, 1024, 0.03125f, sQK, sQK, sS, flag);
            softmax_rows<<<dim3(G * 2048), blk, 0, stream>>>(SBUF, 2048);
            gemm_bt<0, 0, 0, 1><<<dim3(8, 16, G), blk, 0, stream>>>(
                SBUF, VT, nullptr, OUTS + off, 2048, 1024, 2048, 1.f, sS, sQK, sQK, flag);
        }
        write_out<<<8192, blk, 0, stream>>>(OUTS, d_out, NE, flag);
    }
}